// Round 2
// baseline (585.804 us; speedup 1.0000x reference)
//
#include <hip/hip_runtime.h>

typedef __attribute__((ext_vector_type(4))) int i32x4;
typedef unsigned short u16;
typedef unsigned char u8;
typedef unsigned int u32;
typedef unsigned long long u64;

static constexpr int NROW = 16384;   // b*h*w
static constexpr int NCODE = 8192;
static constexpr int ZN = 4194304;   // b*c*h*w
static constexpr int MARGIN_I = 4200;   // 2.5e-4 * 2^24

// Candidate row layout (256 B per row, same 4 MB footprint as before):
//   u16 slots[112]  : 16 groups (code-half*8 + wave) x 7 slots
//   bytes 224..239  : unused
//   bytes 240..255  : u8 counts[16], group g at byte 240+g
static constexpr int GCAP = 7;

// workspace layout (bytes) — 10.6 MB
static constexpr size_t OFF_ZB8  = 0;          // i8 granules z  4 MB
static constexpr size_t OFF_EB8  = 4194304;    // i8 granules e  2 MB
static constexpr size_t OFF_CAND = 6356992;    // 256 B per row  4 MB
static constexpr size_t OFF_LOSS = 10551296;   // float
static constexpr size_t OFF_CTR  = 10551300;   // int

__device__ __forceinline__ char q8(float v, float s) {
  int x = __float2int_rn(v * s);
  x = x < -128 ? -128 : (x > 127 ? 127 : x);
  return (char)x;
}

// ---- numpy fp32 replica (verified rounds 4-9; no FMA contraction) ----
#pragma clang fp contract(off)
__device__ float np_dist(const float* zr, const float* __restrict__ er, float A) {
  const float4* e4 = (const float4*)er;
  float s0 = 0.f, s1 = 0.f, s2 = 0.f, s3 = 0.f;
#pragma unroll 4
  for (int i16 = 0; i16 < 16; ++i16) {
    float4 ea = e4[i16 * 4 + 0], eb = e4[i16 * 4 + 1];
    float4 ec = e4[i16 * 4 + 2], ed = e4[i16 * 4 + 3];
    const float* zz = zr + i16 * 16;
    s0 = __fadd_rn(__fmul_rn(zz[0], ea.x),
         __fadd_rn(__fmul_rn(zz[4], eb.x),
         __fadd_rn(__fmul_rn(zz[8], ec.x),
         __fadd_rn(__fmul_rn(zz[12], ed.x), s0))));
    s1 = __fadd_rn(__fmul_rn(zz[1], ea.y),
         __fadd_rn(__fmul_rn(zz[5], eb.y),
         __fadd_rn(__fmul_rn(zz[9], ec.y),
         __fadd_rn(__fmul_rn(zz[13], ed.y), s1))));
    s2 = __fadd_rn(__fmul_rn(zz[2], ea.z),
         __fadd_rn(__fmul_rn(zz[6], eb.z),
         __fadd_rn(__fmul_rn(zz[10], ec.z),
         __fadd_rn(__fmul_rn(zz[14], ed.z), s2))));
    s3 = __fadd_rn(__fmul_rn(zz[3], ea.w),
         __fadd_rn(__fmul_rn(zz[7], eb.w),
         __fadd_rn(__fmul_rn(zz[11], ec.w),
         __fadd_rn(__fmul_rn(zz[15], ed.w), s3))));
  }
  float C = __fadd_rn(__fadd_rn(s0, s1), __fadd_rn(s2, s3));
  return __fadd_rn(A, -(2.0f * C));
}

// A = np pairwise-sum replica of ||z||^2 (verified rounds 4-9).
__device__ float np_rowA(const float* zrow, int lane, volatile float* red) {
  if (lane < 16) {
    const int half = lane >> 3, jj = lane & 7;
    const float* p = zrow + half * 128 + jj;
    float acc = __fmul_rn(p[0], p[0]);
    for (int i = 8; i < 128; i += 8) acc = __fadd_rn(acc, __fmul_rn(p[i], p[i]));
    red[lane] = acc;
  }
  float h0 = __fadd_rn(__fadd_rn(__fadd_rn(red[0], red[1]), __fadd_rn(red[2], red[3])),
                       __fadd_rn(__fadd_rn(red[4], red[5]), __fadd_rn(red[6], red[7])));
  float h1 = __fadd_rn(__fadd_rn(__fadd_rn(red[8], red[9]), __fadd_rn(red[10], red[11])),
                       __fadd_rn(__fadd_rn(red[12], red[13]), __fadd_rn(red[14], red[15])));
  return __fadd_rn(h0, h1);
}
#pragma clang fp contract(fast)

// ---- kernel 1: prep — z,e -> i8 lane-ordered granules; zero loss/ctr ----
__global__ __launch_bounds__(256) void prep_kernel(const float* __restrict__ z,
                                                   const float* __restrict__ e,
                                                   char* __restrict__ zb8,
                                                   char* __restrict__ eb8,
                                                   float* __restrict__ loss_ws,
                                                   int* __restrict__ ctr) {
  const int blk = blockIdx.x;
  if (blk < 512) {
    __shared__ float t[256][33];
    const int b = blk >> 5, h = blk & 31;
    const int w = threadIdx.x & 31, cc = threadIdx.x >> 5;
    const float* src = z + (size_t)b * 262144 + h * 32 + w;
#pragma unroll
    for (int c0 = 0; c0 < 256; c0 += 8) t[c0 + cc][w] = src[(size_t)(c0 + cc) * 1024];
    if (blk == 0 && threadIdx.x == 0) { *loss_ws = 0.f; *ctr = 0; }
    __syncthreads();
#pragma unroll
    for (int gi = 0; gi < 2; ++gi) {
      const int g = gi * 256 + threadIdx.x;
      const int kb = g >> 7, l4 = (g >> 5) & 3, w2 = g & 31;
      const int c0 = kb * 64 + l4 * 16;
      union { char c[16]; i32x4 v; } u;
#pragma unroll
      for (int j = 0; j < 16; ++j) u.c[j] = q8(t[c0 + j][w2], 16.0f);
      const int tile = blk * 2 + (w2 >> 4);
      *(i32x4*)(zb8 + (size_t)tile * 4096 + (size_t)(kb * 64 + l4 * 16 + (w2 & 15)) * 16) = u.v;
    }
  } else {
    const int G = (blk - 512) * 256 + threadIdx.x;
    const int tile = G >> 8, r = G & 255;
    const int kb = r >> 6, lane = r & 63;
    const int l4 = lane >> 4, l15 = lane & 15;
    const float* s = e + (size_t)(tile * 16 + l15) * 256 + kb * 64 + l4 * 16;
    union { char c[16]; i32x4 v; } u;
#pragma unroll
    for (int j = 0; j < 16; ++j) u.c[j] = q8(s[j], 1048576.0f);
    *(i32x4*)(eb8 + (size_t)G * 16) = u.v;
  }
}

// ---- kernel 2: streaming i8 MFMA scores (round-0 structure) ----
// Push path redesigned: per-(row,half,wave) fixed slot groups, counter in LDS
// (ds_add_rtn ~50cy instead of device atomicAdd ~900cy), candidate store is
// fire-and-forget. Counts written once at kernel end.
__global__ __launch_bounds__(512, 4) void scores_kernel(const char* __restrict__ zb8,
                                                        const char* __restrict__ eb8,
                                                        char* __restrict__ cand) {
  __shared__ int s_rm[64];
  __shared__ u32 s_cnt[64][8];
  const int tid = threadIdx.x;
  const int wave = tid >> 6, lane = tid & 63;
  const int l15 = lane & 15, l4 = lane >> 4;
  const int row0 = (int)(blockIdx.x >> 1) * 64;
  const int half = (int)(blockIdx.x & 1);
  const int code0 = half * 4096;
  const int grp = half * 8 + wave;
  u16* cand16 = (u16*)cand;
  if (tid < 64) s_rm[tid] = INT_MIN;
  s_cnt[tid >> 3][tid & 7] = 0;       // tid<512 covers [64][8]

  i32x4 a[4][4];
#pragma unroll
  for (int rt = 0; rt < 4; ++rt) {
    const i32x4* ab = (const i32x4*)(zb8 + (size_t)((row0 >> 4) + rt) * 4096);
#pragma unroll
    for (int kb = 0; kb < 4; ++kb) a[rt][kb] = ab[kb * 64 + lane];
  }
  __syncthreads();   // s_rm/s_cnt init visible

  const i32x4* ebase = (const i32x4*)eb8;
  int lmax[4][4];

#define COMPUTE(CH, ACC)                                                          \
  i32x4 ACC[4] = {{0,0,0,0},{0,0,0,0},{0,0,0,0},{0,0,0,0}};                       \
  {                                                                               \
    const i32x4* bt = ebase + (size_t)((code0 >> 4) + (CH) * 8 + wave) * 256;     \
    i32x4 bf0 = bt[lane], bf1 = bt[64 + lane], bf2 = bt[128 + lane], bf3 = bt[192 + lane]; \
    _Pragma("unroll")                                                             \
    for (int rt = 0; rt < 4; ++rt) {                                              \
      ACC[rt] = __builtin_amdgcn_mfma_i32_16x16x64_i8(a[rt][0], bf0, ACC[rt], 0, 0, 0); \
      ACC[rt] = __builtin_amdgcn_mfma_i32_16x16x64_i8(a[rt][1], bf1, ACC[rt], 0, 0, 0); \
      ACC[rt] = __builtin_amdgcn_mfma_i32_16x16x64_i8(a[rt][2], bf2, ACC[rt], 0, 0, 0); \
      ACC[rt] = __builtin_amdgcn_mfma_i32_16x16x64_i8(a[rt][3], bf3, ACC[rt], 0, 0, 0); \
    }                                                                             \
  }

#define SYNC_THR()                                                               \
  {                                                                              \
    _Pragma("unroll")                                                            \
    for (int rt = 0; rt < 4; ++rt)                                               \
      _Pragma("unroll")                                                          \
      for (int r = 0; r < 4; ++r) {                                              \
        int m = lmax[rt][r];                                                     \
        _Pragma("unroll")                                                        \
        for (int s = 1; s < 16; s <<= 1) m = max(m, __shfl_xor(m, s));           \
        if (l15 == 0) atomicMax(&s_rm[rt * 16 + l4 * 4 + r], m);                 \
      }                                                                          \
    __syncthreads();                                                             \
    _Pragma("unroll")                                                            \
    for (int rt = 0; rt < 4; ++rt)                                               \
      _Pragma("unroll")                                                          \
      for (int r = 0; r < 4; ++r)                                                \
        lmax[rt][r] = max(lmax[rt][r], s_rm[rt * 16 + l4 * 4 + r]);              \
  }

  // seed: chunks 0..3 (512 codes), maxes only — no pushes against a cold threshold
  for (int ch = 0; ch < 4; ++ch) {
    COMPUTE(ch, acc);
    if (ch == 0) {
#pragma unroll
      for (int rt = 0; rt < 4; ++rt)
#pragma unroll
        for (int r = 0; r < 4; ++r) lmax[rt][r] = acc[rt][r];
    } else {
#pragma unroll
      for (int rt = 0; rt < 4; ++rt)
#pragma unroll
        for (int r = 0; r < 4; ++r) lmax[rt][r] = max(lmax[rt][r], acc[rt][r]);
    }
  }
  SYNC_THR();

  for (int ch = 0; ch < 32; ++ch) {
    COMPUTE(ch, acc);
#pragma unroll
    for (int rt = 0; rt < 4; ++rt)
#pragma unroll
      for (int r = 0; r < 4; ++r) {
        const int v = acc[rt][r];
        if (v > lmax[rt][r] - MARGIN_I) {      // superset of final-threshold set
          const int rl = rt * 16 + l4 * 4 + r;
          u32 p = atomicAdd(&s_cnt[rl][wave], 1u);    // LDS atomic, fast
          if (p < GCAP)
            cand16[(size_t)(row0 + rl) * 128 + grp * GCAP + p] =
                (u16)(code0 + ch * 128 + wave * 16 + l15);
        }
        lmax[rt][r] = max(lmax[rt][r], v);
      }
    if ((ch & 1) == 1 && ch != 31) SYNC_THR();
  }
#undef COMPUTE
#undef SYNC_THR

  // write out per-(row,group) counts — each wave owns its groups exclusively
  __syncthreads();
  {
    const int rl = tid & 63, w = tid >> 6;
    u32 c = s_cnt[rl][w];
    cand[(size_t)(row0 + rl) * 256 + 240 + half * 8 + w] = (u8)(c > 255u ? 255u : c);
  }
}

// ---- kernel 3: pair-compacted numpy-replica rescore + z_st gather + loss ----
__global__ __launch_bounds__(256) void rescore_fin_kernel(const float* __restrict__ z,
                                                          const float* __restrict__ emb,
                                                          const char* __restrict__ cand,
                                                          float* __restrict__ loss_ws,
                                                          int* __restrict__ ctr,
                                                          float* __restrict__ z_st,
                                                          float* __restrict__ out_loss,
                                                          float* __restrict__ out_idx) {
  __shared__ float zrows[32][257];
  __shared__ float red_s[4][16];
  __shared__ float A_s[32], D_s[32];
  __shared__ u64 best_s[32];
  __shared__ int widx_s[32], starts[33], ovf_list[32], rowtot[32];
  __shared__ int nP, nOvf;
  __shared__ u8 cnts8[32][16];
  __shared__ u16 grpoff[32][16];
  __shared__ u8 prow[32 * 112];
  __shared__ u16 pidx[32 * 112];
  const int bh = blockIdx.x;
  const int b = bh >> 5, h = bh & 31;
  const int n0 = bh * 32;
  const int wave = threadIdx.x >> 6, lane = threadIdx.x & 63;
  const u16* cand16 = (const u16*)cand;
  {
    const float* src = z + (size_t)b * 262144 + h * 32;
    const int w = threadIdx.x & 31, c8 = threadIdx.x >> 5;
#pragma unroll
    for (int c0 = 0; c0 < 256; c0 += 8) {
      int c = c0 + c8;
      zrows[w][c] = src[(size_t)c * 1024 + w];
    }
  }
  if (threadIdx.x < 32) best_s[threadIdx.x] = ~0ull;
  __syncthreads();

  for (int j = 0; j < 8; ++j) {
    const int r = wave * 8 + j;
    float A = np_rowA(zrows[r], lane, red_s[wave]);
    if (lane == 0) A_s[r] = A;
  }
  if (threadIdx.x < 32) {
    const int r = threadIdx.x;
    const u32* cw = (const u32*)(cand + (size_t)(n0 + r) * 256 + 240);
    u32 wv[4] = {cw[0], cw[1], cw[2], cw[3]};
    int tot = 0; bool ok = true;
#pragma unroll
    for (int k = 0; k < 16; ++k) {
      u8 c = (u8)((wv[k >> 2] >> ((k & 3) * 8)) & 0xff);
      cnts8[r][k] = c;
      grpoff[r][k] = (u16)tot;
      if (c > GCAP) ok = false;
      tot += c;
    }
    rowtot[r] = ok ? tot : 0;    // overflow rows -> block-wide fallback
  }
  __syncthreads();
  if (threadIdx.x == 0) {
    int acc = 0, no = 0;
    for (int r = 0; r < 32; ++r) {
      starts[r] = acc;
      acc += rowtot[r];
      if (rowtot[r] == 0) ovf_list[no++] = r;
    }
    starts[32] = acc; nP = acc; nOvf = no;
  }
  __syncthreads();
  for (int u = threadIdx.x; u < 512; u += 256) {
    const int r = u >> 4, g = u & 15;
    if (rowtot[r]) {
      const int c = cnts8[r][g];
      const int base = starts[r] + grpoff[r][g];
      for (int j = 0; j < c; ++j) {
        prow[base + j] = (u8)r;
        pidx[base + j] = cand16[(size_t)(n0 + r) * 128 + g * GCAP + j];
      }
    }
  }
  __syncthreads();

  const int P = nP;
  for (int p = threadIdx.x; p < P; p += 256) {
    const int r = prow[p], idx = (int)pidx[p];
    float D = np_dist(zrows[r], emb + (size_t)idx * 256, A_s[r]);
    u64 key = ((u64)__float_as_uint(D) << 16) | (u32)idx;
    atomicMin(&best_s[r], key);
  }
  __syncthreads();

  // overflow fallback (rare): block-wide scan, 32 np_dists/thread per row
  for (int i = 0; i < nOvf; ++i) {
    const int r = ovf_list[i];
    for (int idx = threadIdx.x; idx < NCODE; idx += 256) {
      float D = np_dist(zrows[r], emb + (size_t)idx * 256, A_s[r]);
      u64 k = ((u64)__float_as_uint(D) << 16) | (u32)idx;
      atomicMin(&best_s[r], k);
    }
  }
  if (nOvf) __syncthreads();

  if (threadIdx.x < 32) {
    const int r = threadIdx.x;
    const u64 k = best_s[r];
    const int bidx = (int)(k & 0xFFFF);
    widx_s[r] = bidx;
    out_idx[n0 + r] = (float)bidx;
    D_s[r] = __uint_as_float((u32)(k >> 16));
  }
  __syncthreads();
  if (threadIdx.x == 0) {
    float s = 0.f;
    for (int r = 0; r < 32; ++r) s += D_s[r];
    atomicAdd(loss_ws, s);
    __threadfence();
    int t = atomicAdd(ctr, 1);
    if (t == 511)
      *out_loss = atomicAdd(loss_ws, 0.0f) * (1.25f / 4194304.0f);
  }

  for (int wi = 0; wi < 32; ++wi)
    zrows[wi][threadIdx.x] = emb[(size_t)widx_s[wi] * 256 + threadIdx.x];
  __syncthreads();
  const int w = threadIdx.x & 31, c0 = threadIdx.x >> 5;
  float* dst = z_st + (size_t)b * 262144 + h * 32 + w;
#pragma unroll
  for (int cj = 0; cj < 32; ++cj) {
    int c = c0 + cj * 8;
    dst[(size_t)c * 1024] = zrows[w][c];
  }
}

extern "C" void kernel_launch(void* const* d_in, const int* in_sizes, int n_in,
                              void* d_out, int out_size, void* d_ws, size_t ws_size,
                              hipStream_t stream) {
  const float* z = (const float*)d_in[0];     // fp32 [16,256,32,32]
  const float* emb = (const float*)d_in[1];   // fp32 [8192,256]
  char* ws = (char*)d_ws;
  char* zb8 = ws + OFF_ZB8;
  char* eb8 = ws + OFF_EB8;
  char* cand = ws + OFF_CAND;
  float* loss_ws = (float*)(ws + OFF_LOSS);
  int* ctr = (int*)(ws + OFF_CTR);
  float* out = (float*)d_out;
  float* out_loss = out + ZN;       // output 1
  float* out_idx = out + ZN + 1;    // output 2

  prep_kernel<<<1024, 256, 0, stream>>>(z, emb, zb8, eb8, loss_ws, ctr);
  scores_kernel<<<512, 512, 0, stream>>>(zb8, eb8, cand);
  rescore_fin_kernel<<<512, 256, 0, stream>>>(z, emb, cand, loss_ws, ctr,
                                              out, out_loss, out_idx);
}

// Round 3
// 259.451 us; speedup vs baseline: 2.2579x; 2.2579x over previous
//
#include <hip/hip_runtime.h>

typedef __attribute__((ext_vector_type(4))) int i32x4;
typedef unsigned short u16;
typedef unsigned char u8;
typedef unsigned int u32;
typedef unsigned long long u64;

static constexpr int NROW = 16384;   // b*h*w
static constexpr int NCODE = 8192;
static constexpr int ZN = 4194304;   // b*c*h*w
static constexpr int MARGIN_I = 4200;   // 2.5e-4 * 2^24

// Candidate row layout (256 B per row):
//   u16 slots[96]   : 16 groups (code-half*8 + wave) x 6 slots   (bytes 0..191)
//   u16 ovf[24]     : per-row spill list                          (bytes 192..239)
//   u8  counts[16]  : per-group push counts (saturated)           (bytes 240..255)
// Spill count lives in g_cnt[row]. Full-scan fallback iff g_cnt[row] > OCAP.
static constexpr int GCAP = 6;
static constexpr int OCAP = 24;

// workspace layout (bytes) — 10.6 MB
static constexpr size_t OFF_ZB8  = 0;          // i8 granules z  4 MB
static constexpr size_t OFF_EB8  = 4194304;    // i8 granules e  2 MB
static constexpr size_t OFF_CNT  = 6291456;    // int [NROW] spill counters
static constexpr size_t OFF_CAND = 6356992;    // 256 B per row  4 MB
static constexpr size_t OFF_LOSS = 10551296;   // float
static constexpr size_t OFF_CTR  = 10551300;   // int

__device__ __forceinline__ char q8(float v, float s) {
  int x = __float2int_rn(v * s);
  x = x < -128 ? -128 : (x > 127 ? 127 : x);
  return (char)x;
}

// max over each 16-lane row via DPP row_ror (VALU pipe, no LDS traffic)
__device__ __forceinline__ int rowmax16(int m) {
  m = max(m, __builtin_amdgcn_update_dpp(m, m, 0x121, 0xf, 0xf, false)); // ror:1
  m = max(m, __builtin_amdgcn_update_dpp(m, m, 0x122, 0xf, 0xf, false)); // ror:2
  m = max(m, __builtin_amdgcn_update_dpp(m, m, 0x124, 0xf, 0xf, false)); // ror:4
  m = max(m, __builtin_amdgcn_update_dpp(m, m, 0x128, 0xf, 0xf, false)); // ror:8
  return m;
}

// ---- numpy fp32 replica (verified rounds 4-9; no FMA contraction) ----
#pragma clang fp contract(off)
__device__ float np_dist(const float* zr, const float* __restrict__ er, float A) {
  const float4* e4 = (const float4*)er;
  float s0 = 0.f, s1 = 0.f, s2 = 0.f, s3 = 0.f;
#pragma unroll 4
  for (int i16 = 0; i16 < 16; ++i16) {
    float4 ea = e4[i16 * 4 + 0], eb = e4[i16 * 4 + 1];
    float4 ec = e4[i16 * 4 + 2], ed = e4[i16 * 4 + 3];
    const float* zz = zr + i16 * 16;
    s0 = __fadd_rn(__fmul_rn(zz[0], ea.x),
         __fadd_rn(__fmul_rn(zz[4], eb.x),
         __fadd_rn(__fmul_rn(zz[8], ec.x),
         __fadd_rn(__fmul_rn(zz[12], ed.x), s0))));
    s1 = __fadd_rn(__fmul_rn(zz[1], ea.y),
         __fadd_rn(__fmul_rn(zz[5], eb.y),
         __fadd_rn(__fmul_rn(zz[9], ec.y),
         __fadd_rn(__fmul_rn(zz[13], ed.y), s1))));
    s2 = __fadd_rn(__fmul_rn(zz[2], ea.z),
         __fadd_rn(__fmul_rn(zz[6], eb.z),
         __fadd_rn(__fmul_rn(zz[10], ec.z),
         __fadd_rn(__fmul_rn(zz[14], ed.z), s2))));
    s3 = __fadd_rn(__fmul_rn(zz[3], ea.w),
         __fadd_rn(__fmul_rn(zz[7], eb.w),
         __fadd_rn(__fmul_rn(zz[11], ec.w),
         __fadd_rn(__fmul_rn(zz[15], ed.w), s3))));
  }
  float C = __fadd_rn(__fadd_rn(s0, s1), __fadd_rn(s2, s3));
  return __fadd_rn(A, -(2.0f * C));
}

// A = np pairwise-sum replica of ||z||^2 (verified rounds 4-9).
__device__ float np_rowA(const float* zrow, int lane, volatile float* red) {
  if (lane < 16) {
    const int half = lane >> 3, jj = lane & 7;
    const float* p = zrow + half * 128 + jj;
    float acc = __fmul_rn(p[0], p[0]);
    for (int i = 8; i < 128; i += 8) acc = __fadd_rn(acc, __fmul_rn(p[i], p[i]));
    red[lane] = acc;
  }
  float h0 = __fadd_rn(__fadd_rn(__fadd_rn(red[0], red[1]), __fadd_rn(red[2], red[3])),
                       __fadd_rn(__fadd_rn(red[4], red[5]), __fadd_rn(red[6], red[7])));
  float h1 = __fadd_rn(__fadd_rn(__fadd_rn(red[8], red[9]), __fadd_rn(red[10], red[11])),
                       __fadd_rn(__fadd_rn(red[12], red[13]), __fadd_rn(red[14], red[15])));
  return __fadd_rn(h0, h1);
}
#pragma clang fp contract(fast)

// ---- kernel 1: prep — z,e -> i8 lane-ordered granules; zero cnt/loss/ctr ----
__global__ __launch_bounds__(256) void prep_kernel(const float* __restrict__ z,
                                                   const float* __restrict__ e,
                                                   char* __restrict__ zb8,
                                                   char* __restrict__ eb8,
                                                   int* __restrict__ g_cnt,
                                                   float* __restrict__ loss_ws,
                                                   int* __restrict__ ctr) {
  const int blk = blockIdx.x;
  if (blk < 512) {
    __shared__ float t[256][33];
    const int b = blk >> 5, h = blk & 31;
    const int w = threadIdx.x & 31, cc = threadIdx.x >> 5;
    const float* src = z + (size_t)b * 262144 + h * 32 + w;
#pragma unroll
    for (int c0 = 0; c0 < 256; c0 += 8) t[c0 + cc][w] = src[(size_t)(c0 + cc) * 1024];
    if (threadIdx.x < 32) g_cnt[blk * 32 + threadIdx.x] = 0;
    if (blk == 0 && threadIdx.x == 0) { *loss_ws = 0.f; *ctr = 0; }
    __syncthreads();
#pragma unroll
    for (int gi = 0; gi < 2; ++gi) {
      const int g = gi * 256 + threadIdx.x;
      const int kb = g >> 7, l4 = (g >> 5) & 3, w2 = g & 31;
      const int c0 = kb * 64 + l4 * 16;
      union { char c[16]; i32x4 v; } u;
#pragma unroll
      for (int j = 0; j < 16; ++j) u.c[j] = q8(t[c0 + j][w2], 16.0f);
      const int tile = blk * 2 + (w2 >> 4);
      *(i32x4*)(zb8 + (size_t)tile * 4096 + (size_t)(kb * 64 + l4 * 16 + (w2 & 15)) * 16) = u.v;
    }
  } else {
    const int G = (blk - 512) * 256 + threadIdx.x;
    const int tile = G >> 8, r = G & 255;
    const int kb = r >> 6, lane = r & 63;
    const int l4 = lane >> 4, l15 = lane & 15;
    const float* s = e + (size_t)(tile * 16 + l15) * 256 + kb * 64 + l4 * 16;
    union { char c[16]; i32x4 v; } u;
#pragma unroll
    for (int j = 0; j < 16; ++j) u.c[j] = q8(s[j], 1048576.0f);
    *(i32x4*)(eb8 + (size_t)G * 16) = u.v;
  }
}

// ---- kernel 2: streaming i8 MFMA scores ----
// DPP row-max reduce (no LDS swizzles), lgkm-only barrier (prefetch survives),
// software-pipelined B loads, LDS group counters + rare device-atomic spill tier.
__global__ __launch_bounds__(512, 4) void scores_kernel(const char* __restrict__ zb8,
                                                        const char* __restrict__ eb8,
                                                        int* __restrict__ g_cnt,
                                                        char* __restrict__ cand) {
  __shared__ int s_rm[64];
  __shared__ u32 s_cnt[64][8];
  const int tid = threadIdx.x;
  const int wave = tid >> 6, lane = tid & 63;
  const int l15 = lane & 15, l4 = lane >> 4;
  const int row0 = (int)(blockIdx.x >> 1) * 64;
  const int half = (int)(blockIdx.x & 1);
  const int code0 = half * 4096;
  const int grp = half * 8 + wave;
  u16* cand16 = (u16*)cand;
  if (tid < 64) s_rm[tid] = INT_MIN;
  s_cnt[tid >> 3][tid & 7] = 0;       // tid<512 covers [64][8]

  i32x4 a[4][4];
#pragma unroll
  for (int rt = 0; rt < 4; ++rt) {
    const i32x4* ab = (const i32x4*)(zb8 + (size_t)((row0 >> 4) + rt) * 4096);
#pragma unroll
    for (int kb = 0; kb < 4; ++kb) a[rt][kb] = ab[kb * 64 + lane];
  }
  __syncthreads();   // s_rm/s_cnt init visible

  const i32x4* ebase = (const i32x4*)eb8 + (size_t)(code0 >> 4) * 256;
  int lmax[4][4];

#define LOADB(CH, B0, B1, B2, B3)                                                \
  {                                                                              \
    const i32x4* bt = ebase + (size_t)((CH) * 8 + wave) * 256;                   \
    B0 = bt[lane]; B1 = bt[64 + lane]; B2 = bt[128 + lane]; B3 = bt[192 + lane]; \
  }

#define MFMA_ALL(B0, B1, B2, B3, ACC)                                            \
  _Pragma("unroll")                                                              \
  for (int rt = 0; rt < 4; ++rt) {                                               \
    ACC[rt] = __builtin_amdgcn_mfma_i32_16x16x64_i8(a[rt][0], B0, ACC[rt], 0, 0, 0); \
    ACC[rt] = __builtin_amdgcn_mfma_i32_16x16x64_i8(a[rt][1], B1, ACC[rt], 0, 0, 0); \
    ACC[rt] = __builtin_amdgcn_mfma_i32_16x16x64_i8(a[rt][2], B2, ACC[rt], 0, 0, 0); \
    ACC[rt] = __builtin_amdgcn_mfma_i32_16x16x64_i8(a[rt][3], B3, ACC[rt], 0, 0, 0); \
  }

// s_rm is monotone (atomicMax only, never reset) -> one relaxed barrier is safe;
// drain LDS only so prefetched global loads stay in flight across the barrier.
#define SYNC_THR()                                                               \
  {                                                                              \
    _Pragma("unroll")                                                            \
    for (int rt = 0; rt < 4; ++rt)                                               \
      _Pragma("unroll")                                                          \
      for (int r = 0; r < 4; ++r) {                                              \
        int m = rowmax16(lmax[rt][r]);                                           \
        if (l15 == 0) atomicMax(&s_rm[rt * 16 + l4 * 4 + r], m);                 \
      }                                                                          \
    asm volatile("s_waitcnt lgkmcnt(0)\n\ts_barrier" ::: "memory");              \
    _Pragma("unroll")                                                            \
    for (int rt = 0; rt < 4; ++rt)                                               \
      _Pragma("unroll")                                                          \
      for (int r = 0; r < 4; ++r)                                                \
        lmax[rt][r] = max(lmax[rt][r], s_rm[rt * 16 + l4 * 4 + r]);              \
  }

  // seed: chunks 0..3 (512 codes), maxes only — no pushes against a cold threshold
  {
    i32x4 b0, b1, b2, b3;
#pragma unroll
    for (int ch = 0; ch < 4; ++ch) {
      LOADB(ch, b0, b1, b2, b3);
      i32x4 acc[4] = {{0,0,0,0},{0,0,0,0},{0,0,0,0},{0,0,0,0}};
      MFMA_ALL(b0, b1, b2, b3, acc);
      if (ch == 0) {
#pragma unroll
        for (int rt = 0; rt < 4; ++rt)
#pragma unroll
          for (int r = 0; r < 4; ++r) lmax[rt][r] = acc[rt][r];
      } else {
#pragma unroll
        for (int rt = 0; rt < 4; ++rt)
#pragma unroll
          for (int r = 0; r < 4; ++r) lmax[rt][r] = max(lmax[rt][r], acc[rt][r]);
      }
    }
  }
  SYNC_THR();

  // main loop: depth-1 software pipeline on B fragments
  {
    i32x4 b0, b1, b2, b3, p0, p1, p2, p3;
    LOADB(0, b0, b1, b2, b3);
    for (int ch = 0; ch < 32; ++ch) {
      if (ch < 31) LOADB(ch + 1, p0, p1, p2, p3);
      i32x4 acc[4] = {{0,0,0,0},{0,0,0,0},{0,0,0,0},{0,0,0,0}};
      MFMA_ALL(b0, b1, b2, b3, acc);
#pragma unroll
      for (int rt = 0; rt < 4; ++rt)
#pragma unroll
        for (int r = 0; r < 4; ++r) {
          const int v = acc[rt][r];
          if (v > lmax[rt][r] - MARGIN_I) {      // superset of final-threshold set
            const int rl = rt * 16 + l4 * 4 + r;
            u32 p = atomicAdd(&s_cnt[rl][wave], 1u);   // LDS atomic (fast path)
            if (p < GCAP) {
              cand16[(size_t)(row0 + rl) * 128 + grp * GCAP + p] =
                  (u16)(code0 + ch * 128 + wave * 16 + l15);
            } else {                                   // rare spill tier
              int q = atomicAdd(&g_cnt[row0 + rl], 1);
              if (q < OCAP)
                cand16[(size_t)(row0 + rl) * 128 + 96 + q] =
                    (u16)(code0 + ch * 128 + wave * 16 + l15);
            }
          }
          lmax[rt][r] = max(lmax[rt][r], v);
        }
      if ((ch & 1) == 1 && ch != 31) SYNC_THR();
      b0 = p0; b1 = p1; b2 = p2; b3 = p3;
    }
  }
#undef LOADB
#undef MFMA_ALL
#undef SYNC_THR

  // write out per-(row,group) counts — each wave owns its groups exclusively
  __syncthreads();
  {
    const int rl = tid & 63, w = tid >> 6;
    u32 c = s_cnt[rl][w];
    cand[(size_t)(row0 + rl) * 256 + 240 + half * 8 + w] = (u8)(c > 255u ? 255u : c);
  }
}

// ---- kernel 3: pair-compacted numpy-replica rescore + z_st gather + loss ----
__global__ __launch_bounds__(256) void rescore_fin_kernel(const float* __restrict__ z,
                                                          const float* __restrict__ emb,
                                                          const int* __restrict__ g_cnt,
                                                          const char* __restrict__ cand,
                                                          float* __restrict__ loss_ws,
                                                          int* __restrict__ ctr,
                                                          float* __restrict__ z_st,
                                                          float* __restrict__ out_loss,
                                                          float* __restrict__ out_idx) {
  __shared__ float zrows[32][257];
  __shared__ float red_s[4][16];
  __shared__ float A_s[32], D_s[32];
  __shared__ u64 best_s[32];
  __shared__ int widx_s[32], starts[33], ovf_list[32], rowtot[32];
  __shared__ int nP, nOvf;
  __shared__ u8 cnts8[32][17];
  __shared__ u16 grpoff[32][17];
  __shared__ u8 prow[32 * 120];
  __shared__ u16 pidx[32 * 120];
  const int bh = blockIdx.x;
  const int b = bh >> 5, h = bh & 31;
  const int n0 = bh * 32;
  const int wave = threadIdx.x >> 6, lane = threadIdx.x & 63;
  const u16* cand16 = (const u16*)cand;
  {
    const float* src = z + (size_t)b * 262144 + h * 32;
    const int w = threadIdx.x & 31, c8 = threadIdx.x >> 5;
#pragma unroll
    for (int c0 = 0; c0 < 256; c0 += 8) {
      int c = c0 + c8;
      zrows[w][c] = src[(size_t)c * 1024 + w];
    }
  }
  if (threadIdx.x < 32) best_s[threadIdx.x] = ~0ull;
  __syncthreads();

  for (int j = 0; j < 8; ++j) {
    const int r = wave * 8 + j;
    float A = np_rowA(zrows[r], lane, red_s[wave]);
    if (lane == 0) A_s[r] = A;
  }
  if (threadIdx.x < 32) {
    const int r = threadIdx.x;
    const u32* cw = (const u32*)(cand + (size_t)(n0 + r) * 256 + 240);
    u32 wv[4] = {cw[0], cw[1], cw[2], cw[3]};
    int tot = 0;
#pragma unroll
    for (int k = 0; k < 16; ++k) {
      int c = (int)((wv[k >> 2] >> ((k & 3) * 8)) & 0xff);
      int cc = c > GCAP ? GCAP : c;
      cnts8[r][k] = (u8)cc;
      grpoff[r][k] = (u16)tot;
      tot += cc;
    }
    const int ov = g_cnt[n0 + r];
    const int oc = ov > OCAP ? OCAP : ov;
    cnts8[r][16] = (u8)oc;
    grpoff[r][16] = (u16)tot;
    tot += oc;
    rowtot[r] = (ov > OCAP) ? 0 : tot;   // 0 -> block-wide full-scan fallback
  }
  __syncthreads();
  if (threadIdx.x == 0) {
    int acc = 0, no = 0;
    for (int r = 0; r < 32; ++r) {
      starts[r] = acc;
      acc += rowtot[r];
      if (rowtot[r] == 0) ovf_list[no++] = r;
    }
    starts[32] = acc; nP = acc; nOvf = no;
  }
  __syncthreads();
  for (int u = threadIdx.x; u < 512; u += 256) {
    const int r = u >> 4, g = u & 15;
    if (rowtot[r]) {
      const int c = cnts8[r][g];
      const int base = starts[r] + grpoff[r][g];
      const int sb = g * GCAP;
      for (int j = 0; j < c; ++j) {
        prow[base + j] = (u8)r;
        pidx[base + j] = cand16[(size_t)(n0 + r) * 128 + sb + j];
      }
    }
  }
  if (threadIdx.x < 32) {
    const int r = threadIdx.x;
    if (rowtot[r]) {
      const int c = cnts8[r][16];
      const int base = starts[r] + grpoff[r][16];
      for (int j = 0; j < c; ++j) {
        prow[base + j] = (u8)r;
        pidx[base + j] = cand16[(size_t)(n0 + r) * 128 + 96 + j];
      }
    }
  }
  __syncthreads();

  const int P = nP;
  for (int p = threadIdx.x; p < P; p += 256) {
    const int r = prow[p], idx = (int)pidx[p];
    float D = np_dist(zrows[r], emb + (size_t)idx * 256, A_s[r]);
    u64 key = ((u64)__float_as_uint(D) << 16) | (u32)idx;
    atomicMin(&best_s[r], key);
  }
  __syncthreads();

  // overflow fallback (spill>OCAP, ~never): block-wide scan
  for (int i = 0; i < nOvf; ++i) {
    const int r = ovf_list[i];
    for (int idx = threadIdx.x; idx < NCODE; idx += 256) {
      float D = np_dist(zrows[r], emb + (size_t)idx * 256, A_s[r]);
      u64 k = ((u64)__float_as_uint(D) << 16) | (u32)idx;
      atomicMin(&best_s[r], k);
    }
  }
  if (nOvf) __syncthreads();

  if (threadIdx.x < 32) {
    const int r = threadIdx.x;
    const u64 k = best_s[r];
    const int bidx = (int)(k & 0xFFFF);
    widx_s[r] = bidx;
    out_idx[n0 + r] = (float)bidx;
    D_s[r] = __uint_as_float((u32)(k >> 16));
  }
  __syncthreads();
  if (threadIdx.x == 0) {
    float s = 0.f;
    for (int r = 0; r < 32; ++r) s += D_s[r];
    atomicAdd(loss_ws, s);
    __threadfence();
    int t = atomicAdd(ctr, 1);
    if (t == 511)
      *out_loss = atomicAdd(loss_ws, 0.0f) * (1.25f / 4194304.0f);
  }

  for (int wi = 0; wi < 32; ++wi)
    zrows[wi][threadIdx.x] = emb[(size_t)widx_s[wi] * 256 + threadIdx.x];
  __syncthreads();
  const int w = threadIdx.x & 31, c0 = threadIdx.x >> 5;
  float* dst = z_st + (size_t)b * 262144 + h * 32 + w;
#pragma unroll
  for (int cj = 0; cj < 32; ++cj) {
    int c = c0 + cj * 8;
    dst[(size_t)c * 1024] = zrows[w][c];
  }
}

extern "C" void kernel_launch(void* const* d_in, const int* in_sizes, int n_in,
                              void* d_out, int out_size, void* d_ws, size_t ws_size,
                              hipStream_t stream) {
  const float* z = (const float*)d_in[0];     // fp32 [16,256,32,32]
  const float* emb = (const float*)d_in[1];   // fp32 [8192,256]
  char* ws = (char*)d_ws;
  char* zb8 = ws + OFF_ZB8;
  char* eb8 = ws + OFF_EB8;
  int* g_cnt = (int*)(ws + OFF_CNT);
  char* cand = ws + OFF_CAND;
  float* loss_ws = (float*)(ws + OFF_LOSS);
  int* ctr = (int*)(ws + OFF_CTR);
  float* out = (float*)d_out;
  float* out_loss = out + ZN;       // output 1
  float* out_idx = out + ZN + 1;    // output 2

  prep_kernel<<<1024, 256, 0, stream>>>(z, emb, zb8, eb8, g_cnt, loss_ws, ctr);
  scores_kernel<<<512, 512, 0, stream>>>(zb8, eb8, g_cnt, cand);
  rescore_fin_kernel<<<512, 256, 0, stream>>>(z, emb, g_cnt, cand, loss_ws, ctr,
                                              out, out_loss, out_idx);
}

// Round 4
// 250.546 us; speedup vs baseline: 2.3381x; 1.0355x over previous
//
#include <hip/hip_runtime.h>

typedef __attribute__((ext_vector_type(4))) int i32x4;
typedef unsigned short u16;
typedef unsigned char u8;
typedef unsigned int u32;
typedef unsigned long long u64;

static constexpr int NROW = 16384;   // b*h*w
static constexpr int NCODE = 8192;
static constexpr int ZN = 4194304;   // b*c*h*w
static constexpr int MARGIN_I = 4200;   // 2.5e-4 * 2^24

// Candidate row layout (256 B per row):
//   u16 slots[96]   : 16 groups (code-half*8 + wave) x 6 slots   (bytes 0..191)
//   u16 ovf[24]     : per-row spill list                          (bytes 192..239)
//   u8  counts[16]  : per-group push counts (saturated)           (bytes 240..255)
// Spill count lives in g_cnt[row]. Full-scan fallback iff g_cnt[row] > OCAP.
static constexpr int GCAP = 6;
static constexpr int OCAP = 24;

// workspace layout (bytes) — 10.6 MB
static constexpr size_t OFF_ZB8  = 0;          // i8 granules z  4 MB
static constexpr size_t OFF_EB8  = 4194304;    // i8 granules e  2 MB
static constexpr size_t OFF_CNT  = 6291456;    // int [NROW] spill counters
static constexpr size_t OFF_CAND = 6356992;    // 256 B per row  4 MB
static constexpr size_t OFF_LOSS = 10551296;   // float
static constexpr size_t OFF_CTR  = 10551300;   // int

__device__ __forceinline__ char q8(float v, float s) {
  int x = __float2int_rn(v * s);
  x = x < -128 ? -128 : (x > 127 ? 127 : x);
  return (char)x;
}

// max over each 16-lane row via DPP row_ror (VALU pipe, no LDS traffic)
__device__ __forceinline__ int rowmax16(int m) {
  m = max(m, __builtin_amdgcn_update_dpp(m, m, 0x121, 0xf, 0xf, false)); // ror:1
  m = max(m, __builtin_amdgcn_update_dpp(m, m, 0x122, 0xf, 0xf, false)); // ror:2
  m = max(m, __builtin_amdgcn_update_dpp(m, m, 0x124, 0xf, 0xf, false)); // ror:4
  m = max(m, __builtin_amdgcn_update_dpp(m, m, 0x128, 0xf, 0xf, false)); // ror:8
  return m;
}

// ---- numpy fp32 replica (verified rounds 4-9; no FMA contraction) ----
#pragma clang fp contract(off)
__device__ float np_dist(const float* zr, const float* __restrict__ er, float A) {
  const float4* e4 = (const float4*)er;
  float s0 = 0.f, s1 = 0.f, s2 = 0.f, s3 = 0.f;
#pragma unroll 4
  for (int i16 = 0; i16 < 16; ++i16) {
    float4 ea = e4[i16 * 4 + 0], eb = e4[i16 * 4 + 1];
    float4 ec = e4[i16 * 4 + 2], ed = e4[i16 * 4 + 3];
    const float* zz = zr + i16 * 16;
    s0 = __fadd_rn(__fmul_rn(zz[0], ea.x),
         __fadd_rn(__fmul_rn(zz[4], eb.x),
         __fadd_rn(__fmul_rn(zz[8], ec.x),
         __fadd_rn(__fmul_rn(zz[12], ed.x), s0))));
    s1 = __fadd_rn(__fmul_rn(zz[1], ea.y),
         __fadd_rn(__fmul_rn(zz[5], eb.y),
         __fadd_rn(__fmul_rn(zz[9], ec.y),
         __fadd_rn(__fmul_rn(zz[13], ed.y), s1))));
    s2 = __fadd_rn(__fmul_rn(zz[2], ea.z),
         __fadd_rn(__fmul_rn(zz[6], eb.z),
         __fadd_rn(__fmul_rn(zz[10], ec.z),
         __fadd_rn(__fmul_rn(zz[14], ed.z), s2))));
    s3 = __fadd_rn(__fmul_rn(zz[3], ea.w),
         __fadd_rn(__fmul_rn(zz[7], eb.w),
         __fadd_rn(__fmul_rn(zz[11], ec.w),
         __fadd_rn(__fmul_rn(zz[15], ed.w), s3))));
  }
  float C = __fadd_rn(__fadd_rn(s0, s1), __fadd_rn(s2, s3));
  return __fadd_rn(A, -(2.0f * C));
}

// A = np pairwise-sum replica of ||z||^2 (verified rounds 4-9).
__device__ float np_rowA(const float* zrow, int lane, volatile float* red) {
  if (lane < 16) {
    const int half = lane >> 3, jj = lane & 7;
    const float* p = zrow + half * 128 + jj;
    float acc = __fmul_rn(p[0], p[0]);
    for (int i = 8; i < 128; i += 8) acc = __fadd_rn(acc, __fmul_rn(p[i], p[i]));
    red[lane] = acc;
  }
  float h0 = __fadd_rn(__fadd_rn(__fadd_rn(red[0], red[1]), __fadd_rn(red[2], red[3])),
                       __fadd_rn(__fadd_rn(red[4], red[5]), __fadd_rn(red[6], red[7])));
  float h1 = __fadd_rn(__fadd_rn(__fadd_rn(red[8], red[9]), __fadd_rn(red[10], red[11])),
                       __fadd_rn(__fadd_rn(red[12], red[13]), __fadd_rn(red[14], red[15])));
  return __fadd_rn(h0, h1);
}
#pragma clang fp contract(fast)

// ---- kernel 1: prep — z,e -> i8 lane-ordered granules; zero cnt/loss/ctr ----
__global__ __launch_bounds__(256) void prep_kernel(const float* __restrict__ z,
                                                   const float* __restrict__ e,
                                                   char* __restrict__ zb8,
                                                   char* __restrict__ eb8,
                                                   int* __restrict__ g_cnt,
                                                   float* __restrict__ loss_ws,
                                                   int* __restrict__ ctr) {
  const int blk = blockIdx.x;
  if (blk < 512) {
    __shared__ float t[256][33];
    const int b = blk >> 5, h = blk & 31;
    const int w = threadIdx.x & 31, cc = threadIdx.x >> 5;
    const float* src = z + (size_t)b * 262144 + h * 32 + w;
#pragma unroll
    for (int c0 = 0; c0 < 256; c0 += 8) t[c0 + cc][w] = src[(size_t)(c0 + cc) * 1024];
    if (threadIdx.x < 32) g_cnt[blk * 32 + threadIdx.x] = 0;
    if (blk == 0 && threadIdx.x == 0) { *loss_ws = 0.f; *ctr = 0; }
    __syncthreads();
#pragma unroll
    for (int gi = 0; gi < 2; ++gi) {
      const int g = gi * 256 + threadIdx.x;
      const int kb = g >> 7, l4 = (g >> 5) & 3, w2 = g & 31;
      const int c0 = kb * 64 + l4 * 16;
      union { char c[16]; i32x4 v; } u;
#pragma unroll
      for (int j = 0; j < 16; ++j) u.c[j] = q8(t[c0 + j][w2], 16.0f);
      const int tile = blk * 2 + (w2 >> 4);
      *(i32x4*)(zb8 + (size_t)tile * 4096 + (size_t)(kb * 64 + l4 * 16 + (w2 & 15)) * 16) = u.v;
    }
  } else {
    const int G = (blk - 512) * 256 + threadIdx.x;
    const int tile = G >> 8, r = G & 255;
    const int kb = r >> 6, lane = r & 63;
    const int l4 = lane >> 4, l15 = lane & 15;
    const float* s = e + (size_t)(tile * 16 + l15) * 256 + kb * 64 + l4 * 16;
    union { char c[16]; i32x4 v; } u;
#pragma unroll
    for (int j = 0; j < 16; ++j) u.c[j] = q8(s[j], 1048576.0f);
    *(i32x4*)(eb8 + (size_t)G * 16) = u.v;
  }
}

// ---- kernel 2: streaming i8 MFMA scores ----
// launch_bounds(512,2): grid is 2 blocks/CU max anyway — the old (512,4) forced a
// 64-reg budget against a ~130-reg live set and spilled to scratch every chunk
// (round-3 counters: WRITE 98MB, ~343 B/thread of spill stores). 128 regs fits.
__global__ __launch_bounds__(512, 2) void scores_kernel(const char* __restrict__ zb8,
                                                        const char* __restrict__ eb8,
                                                        int* __restrict__ g_cnt,
                                                        char* __restrict__ cand) {
  __shared__ int s_rm[64];
  __shared__ u32 s_cnt[64][8];
  const int tid = threadIdx.x;
  const int wave = tid >> 6, lane = tid & 63;
  const int l15 = lane & 15, l4 = lane >> 4;
  const int row0 = (int)(blockIdx.x >> 1) * 64;
  const int half = (int)(blockIdx.x & 1);
  const int code0 = half * 4096;
  const int grp = half * 8 + wave;
  u16* cand16 = (u16*)cand;
  if (tid < 64) s_rm[tid] = INT_MIN;
  s_cnt[tid >> 3][tid & 7] = 0;       // tid<512 covers [64][8]

  i32x4 a[4][4];
#pragma unroll
  for (int rt = 0; rt < 4; ++rt) {
    const i32x4* ab = (const i32x4*)(zb8 + (size_t)((row0 >> 4) + rt) * 4096);
#pragma unroll
    for (int kb = 0; kb < 4; ++kb) a[rt][kb] = ab[kb * 64 + lane];
  }
  __syncthreads();   // s_rm/s_cnt init visible

  const i32x4* ebase = (const i32x4*)eb8 + (size_t)(code0 >> 4) * 256;
  int lmax[4][4];

#define COMPUTE(CH, ACC)                                                          \
  i32x4 ACC[4] = {{0,0,0,0},{0,0,0,0},{0,0,0,0},{0,0,0,0}};                       \
  {                                                                               \
    const i32x4* bt = ebase + (size_t)((CH) * 8 + wave) * 256;                    \
    i32x4 bf0 = bt[lane], bf1 = bt[64 + lane], bf2 = bt[128 + lane], bf3 = bt[192 + lane]; \
    _Pragma("unroll")                                                             \
    for (int rt = 0; rt < 4; ++rt) {                                              \
      ACC[rt] = __builtin_amdgcn_mfma_i32_16x16x64_i8(a[rt][0], bf0, ACC[rt], 0, 0, 0); \
      ACC[rt] = __builtin_amdgcn_mfma_i32_16x16x64_i8(a[rt][1], bf1, ACC[rt], 0, 0, 0); \
      ACC[rt] = __builtin_amdgcn_mfma_i32_16x16x64_i8(a[rt][2], bf2, ACC[rt], 0, 0, 0); \
      ACC[rt] = __builtin_amdgcn_mfma_i32_16x16x64_i8(a[rt][3], bf3, ACC[rt], 0, 0, 0); \
    }                                                                             \
  }

// s_rm is monotone (atomicMax only, never reset) -> one relaxed barrier is safe;
// drain LDS only so in-flight global loads survive the barrier.
#define SYNC_THR()                                                               \
  {                                                                              \
    _Pragma("unroll")                                                            \
    for (int rt = 0; rt < 4; ++rt)                                               \
      _Pragma("unroll")                                                          \
      for (int r = 0; r < 4; ++r) {                                              \
        int m = rowmax16(lmax[rt][r]);                                           \
        if (l15 == 0) atomicMax(&s_rm[rt * 16 + l4 * 4 + r], m);                 \
      }                                                                          \
    asm volatile("s_waitcnt lgkmcnt(0)\n\ts_barrier" ::: "memory");              \
    _Pragma("unroll")                                                            \
    for (int rt = 0; rt < 4; ++rt)                                               \
      _Pragma("unroll")                                                          \
      for (int r = 0; r < 4; ++r)                                                \
        lmax[rt][r] = max(lmax[rt][r], s_rm[rt * 16 + l4 * 4 + r]);              \
  }

  // seed: chunks 0..3 (512 codes), maxes only — no pushes against a cold threshold
  for (int ch = 0; ch < 4; ++ch) {
    COMPUTE(ch, acc);
    if (ch == 0) {
#pragma unroll
      for (int rt = 0; rt < 4; ++rt)
#pragma unroll
        for (int r = 0; r < 4; ++r) lmax[rt][r] = acc[rt][r];
    } else {
#pragma unroll
      for (int rt = 0; rt < 4; ++rt)
#pragma unroll
        for (int r = 0; r < 4; ++r) lmax[rt][r] = max(lmax[rt][r], acc[rt][r]);
    }
  }
  SYNC_THR();

  for (int ch = 0; ch < 32; ++ch) {
    COMPUTE(ch, acc);
#pragma unroll
    for (int rt = 0; rt < 4; ++rt)
#pragma unroll
      for (int r = 0; r < 4; ++r) {
        const int v = acc[rt][r];
        if (v > lmax[rt][r] - MARGIN_I) {      // superset of final-threshold set
          const int rl = rt * 16 + l4 * 4 + r;
          u32 p = atomicAdd(&s_cnt[rl][wave], 1u);   // LDS atomic (fast path)
          if (p < GCAP) {
            cand16[(size_t)(row0 + rl) * 128 + grp * GCAP + p] =
                (u16)(code0 + ch * 128 + wave * 16 + l15);
          } else {                                   // rare spill tier
            int q = atomicAdd(&g_cnt[row0 + rl], 1);
            if (q < OCAP)
              cand16[(size_t)(row0 + rl) * 128 + 96 + q] =
                  (u16)(code0 + ch * 128 + wave * 16 + l15);
          }
        }
        lmax[rt][r] = max(lmax[rt][r], v);
      }
    if ((ch & 1) == 1 && ch != 31) SYNC_THR();
  }
#undef COMPUTE
#undef SYNC_THR

  // write out per-(row,group) counts — each wave owns its groups exclusively
  __syncthreads();
  {
    const int rl = tid & 63, w = tid >> 6;
    u32 c = s_cnt[rl][w];
    cand[(size_t)(row0 + rl) * 256 + 240 + half * 8 + w] = (u8)(c > 255u ? 255u : c);
  }
}

// ---- kernel 3: pair-compacted numpy-replica rescore + z_st gather + loss ----
__global__ __launch_bounds__(256) void rescore_fin_kernel(const float* __restrict__ z,
                                                          const float* __restrict__ emb,
                                                          const int* __restrict__ g_cnt,
                                                          const char* __restrict__ cand,
                                                          float* __restrict__ loss_ws,
                                                          int* __restrict__ ctr,
                                                          float* __restrict__ z_st,
                                                          float* __restrict__ out_loss,
                                                          float* __restrict__ out_idx) {
  __shared__ float zrows[32][257];
  __shared__ float red_s[4][16];
  __shared__ float A_s[32], D_s[32];
  __shared__ u64 best_s[32];
  __shared__ int widx_s[32], starts[33], ovf_list[32], rowtot[32];
  __shared__ int nP, nOvf;
  __shared__ u8 cnts8[32][17];
  __shared__ u16 grpoff[32][17];
  __shared__ u8 prow[32 * 120];
  __shared__ u16 pidx[32 * 120];
  const int bh = blockIdx.x;
  const int b = bh >> 5, h = bh & 31;
  const int n0 = bh * 32;
  const int wave = threadIdx.x >> 6, lane = threadIdx.x & 63;
  const u16* cand16 = (const u16*)cand;
  {
    const float* src = z + (size_t)b * 262144 + h * 32;
    const int w = threadIdx.x & 31, c8 = threadIdx.x >> 5;
#pragma unroll
    for (int c0 = 0; c0 < 256; c0 += 8) {
      int c = c0 + c8;
      zrows[w][c] = src[(size_t)c * 1024 + w];
    }
  }
  if (threadIdx.x < 32) best_s[threadIdx.x] = ~0ull;
  __syncthreads();

  for (int j = 0; j < 8; ++j) {
    const int r = wave * 8 + j;
    float A = np_rowA(zrows[r], lane, red_s[wave]);
    if (lane == 0) A_s[r] = A;
  }
  if (threadIdx.x < 32) {
    const int r = threadIdx.x;
    const u32* cw = (const u32*)(cand + (size_t)(n0 + r) * 256 + 240);
    u32 wv[4] = {cw[0], cw[1], cw[2], cw[3]};
    int tot = 0;
#pragma unroll
    for (int k = 0; k < 16; ++k) {
      int c = (int)((wv[k >> 2] >> ((k & 3) * 8)) & 0xff);
      int cc = c > GCAP ? GCAP : c;
      cnts8[r][k] = (u8)cc;
      grpoff[r][k] = (u16)tot;
      tot += cc;
    }
    const int ov = g_cnt[n0 + r];
    const int oc = ov > OCAP ? OCAP : ov;
    cnts8[r][16] = (u8)oc;
    grpoff[r][16] = (u16)tot;
    tot += oc;
    rowtot[r] = (ov > OCAP) ? 0 : tot;   // 0 -> block-wide full-scan fallback
  }
  __syncthreads();
  if (threadIdx.x == 0) {
    int acc = 0, no = 0;
    for (int r = 0; r < 32; ++r) {
      starts[r] = acc;
      acc += rowtot[r];
      if (rowtot[r] == 0) ovf_list[no++] = r;
    }
    starts[32] = acc; nP = acc; nOvf = no;
  }
  __syncthreads();
  for (int u = threadIdx.x; u < 512; u += 256) {
    const int r = u >> 4, g = u & 15;
    if (rowtot[r]) {
      const int c = cnts8[r][g];
      const int base = starts[r] + grpoff[r][g];
      const int sb = g * GCAP;
      for (int j = 0; j < c; ++j) {
        prow[base + j] = (u8)r;
        pidx[base + j] = cand16[(size_t)(n0 + r) * 128 + sb + j];
      }
    }
  }
  if (threadIdx.x < 32) {
    const int r = threadIdx.x;
    if (rowtot[r]) {
      const int c = cnts8[r][16];
      const int base = starts[r] + grpoff[r][16];
      for (int j = 0; j < c; ++j) {
        prow[base + j] = (u8)r;
        pidx[base + j] = cand16[(size_t)(n0 + r) * 128 + 96 + j];
      }
    }
  }
  __syncthreads();

  const int P = nP;
  for (int p = threadIdx.x; p < P; p += 256) {
    const int r = prow[p], idx = (int)pidx[p];
    float D = np_dist(zrows[r], emb + (size_t)idx * 256, A_s[r]);
    u64 key = ((u64)__float_as_uint(D) << 16) | (u32)idx;
    atomicMin(&best_s[r], key);
  }
  __syncthreads();

  // overflow fallback (spill>OCAP, ~never): block-wide scan
  for (int i = 0; i < nOvf; ++i) {
    const int r = ovf_list[i];
    for (int idx = threadIdx.x; idx < NCODE; idx += 256) {
      float D = np_dist(zrows[r], emb + (size_t)idx * 256, A_s[r]);
      u64 k = ((u64)__float_as_uint(D) << 16) | (u32)idx;
      atomicMin(&best_s[r], k);
    }
  }
  if (nOvf) __syncthreads();

  if (threadIdx.x < 32) {
    const int r = threadIdx.x;
    const u64 k = best_s[r];
    const int bidx = (int)(k & 0xFFFF);
    widx_s[r] = bidx;
    out_idx[n0 + r] = (float)bidx;
    D_s[r] = __uint_as_float((u32)(k >> 16));
  }
  __syncthreads();
  if (threadIdx.x == 0) {
    float s = 0.f;
    for (int r = 0; r < 32; ++r) s += D_s[r];
    atomicAdd(loss_ws, s);
    __threadfence();
    int t = atomicAdd(ctr, 1);
    if (t == 511)
      *out_loss = atomicAdd(loss_ws, 0.0f) * (1.25f / 4194304.0f);
  }

  for (int wi = 0; wi < 32; ++wi)
    zrows[wi][threadIdx.x] = emb[(size_t)widx_s[wi] * 256 + threadIdx.x];
  __syncthreads();
  const int w = threadIdx.x & 31, c0 = threadIdx.x >> 5;
  float* dst = z_st + (size_t)b * 262144 + h * 32 + w;
#pragma unroll
  for (int cj = 0; cj < 32; ++cj) {
    int c = c0 + cj * 8;
    dst[(size_t)c * 1024] = zrows[w][c];
  }
}

extern "C" void kernel_launch(void* const* d_in, const int* in_sizes, int n_in,
                              void* d_out, int out_size, void* d_ws, size_t ws_size,
                              hipStream_t stream) {
  const float* z = (const float*)d_in[0];     // fp32 [16,256,32,32]
  const float* emb = (const float*)d_in[1];   // fp32 [8192,256]
  char* ws = (char*)d_ws;
  char* zb8 = ws + OFF_ZB8;
  char* eb8 = ws + OFF_EB8;
  int* g_cnt = (int*)(ws + OFF_CNT);
  char* cand = ws + OFF_CAND;
  float* loss_ws = (float*)(ws + OFF_LOSS);
  int* ctr = (int*)(ws + OFF_CTR);
  float* out = (float*)d_out;
  float* out_loss = out + ZN;       // output 1
  float* out_idx = out + ZN + 1;    // output 2

  prep_kernel<<<1024, 256, 0, stream>>>(z, emb, zb8, eb8, g_cnt, loss_ws, ctr);
  scores_kernel<<<512, 512, 0, stream>>>(zb8, eb8, g_cnt, cand);
  rescore_fin_kernel<<<512, 256, 0, stream>>>(z, emb, g_cnt, cand, loss_ws, ctr,
                                              out, out_loss, out_idx);
}

// Round 5
// 234.953 us; speedup vs baseline: 2.4933x; 1.0664x over previous
//
#include <hip/hip_runtime.h>

typedef __attribute__((ext_vector_type(4))) int i32x4;
typedef unsigned short u16;
typedef unsigned char u8;
typedef unsigned int u32;
typedef unsigned long long u64;

static constexpr int NROW = 16384;   // b*h*w
static constexpr int NCODE = 8192;
static constexpr int ZN = 4194304;   // b*c*h*w
static constexpr int MARGIN_I = 4200;   // 2.5e-4 * 2^24

// Candidate row layout (256 B per row):
//   u16 slots[96]   : 16 groups (code-half*8 + wave) x 6 slots   (bytes 0..191)
//   u16 ovf[24]     : per-row spill list                          (bytes 192..239)
//   u8  counts[16]  : per-group push counts (saturated)           (bytes 240..255)
// Spill count lives in g_cnt[row]. Full-scan fallback iff g_cnt[row] > OCAP.
static constexpr int GCAP = 6;
static constexpr int OCAP = 24;

// workspace layout (bytes) — 10.6 MB
static constexpr size_t OFF_ZB8  = 0;          // i8 granules z  4 MB
static constexpr size_t OFF_EB8  = 4194304;    // i8 granules e  2 MB
static constexpr size_t OFF_CNT  = 6291456;    // int [NROW] spill counters
static constexpr size_t OFF_CAND = 6356992;    // 256 B per row  4 MB
static constexpr size_t OFF_LOSS = 10551296;   // float
static constexpr size_t OFF_CTR  = 10551300;   // int

__device__ __forceinline__ char q8(float v, float s) {
  int x = __float2int_rn(v * s);
  x = x < -128 ? -128 : (x > 127 ? 127 : x);
  return (char)x;
}

// max over each 16-lane row via DPP row_ror (VALU pipe, no LDS traffic)
__device__ __forceinline__ int rowmax16(int m) {
  m = max(m, __builtin_amdgcn_update_dpp(m, m, 0x121, 0xf, 0xf, false)); // ror:1
  m = max(m, __builtin_amdgcn_update_dpp(m, m, 0x122, 0xf, 0xf, false)); // ror:2
  m = max(m, __builtin_amdgcn_update_dpp(m, m, 0x124, 0xf, 0xf, false)); // ror:4
  m = max(m, __builtin_amdgcn_update_dpp(m, m, 0x128, 0xf, 0xf, false)); // ror:8
  return m;
}

// ---- numpy fp32 replica (verified rounds 4-9; no FMA contraction) ----
#pragma clang fp contract(off)
__device__ float np_dist(const float* zr, const float* __restrict__ er, float A) {
  const float4* e4 = (const float4*)er;
  float s0 = 0.f, s1 = 0.f, s2 = 0.f, s3 = 0.f;
#pragma unroll 4
  for (int i16 = 0; i16 < 16; ++i16) {
    float4 ea = e4[i16 * 4 + 0], eb = e4[i16 * 4 + 1];
    float4 ec = e4[i16 * 4 + 2], ed = e4[i16 * 4 + 3];
    const float* zz = zr + i16 * 16;
    s0 = __fadd_rn(__fmul_rn(zz[0], ea.x),
         __fadd_rn(__fmul_rn(zz[4], eb.x),
         __fadd_rn(__fmul_rn(zz[8], ec.x),
         __fadd_rn(__fmul_rn(zz[12], ed.x), s0))));
    s1 = __fadd_rn(__fmul_rn(zz[1], ea.y),
         __fadd_rn(__fmul_rn(zz[5], eb.y),
         __fadd_rn(__fmul_rn(zz[9], ec.y),
         __fadd_rn(__fmul_rn(zz[13], ed.y), s1))));
    s2 = __fadd_rn(__fmul_rn(zz[2], ea.z),
         __fadd_rn(__fmul_rn(zz[6], eb.z),
         __fadd_rn(__fmul_rn(zz[10], ec.z),
         __fadd_rn(__fmul_rn(zz[14], ed.z), s2))));
    s3 = __fadd_rn(__fmul_rn(zz[3], ea.w),
         __fadd_rn(__fmul_rn(zz[7], eb.w),
         __fadd_rn(__fmul_rn(zz[11], ec.w),
         __fadd_rn(__fmul_rn(zz[15], ed.w), s3))));
  }
  float C = __fadd_rn(__fadd_rn(s0, s1), __fadd_rn(s2, s3));
  return __fadd_rn(A, -(2.0f * C));
}

// A = np pairwise-sum replica of ||z||^2 (verified rounds 4-9).
__device__ float np_rowA(const float* zrow, int lane, volatile float* red) {
  if (lane < 16) {
    const int half = lane >> 3, jj = lane & 7;
    const float* p = zrow + half * 128 + jj;
    float acc = __fmul_rn(p[0], p[0]);
    for (int i = 8; i < 128; i += 8) acc = __fadd_rn(acc, __fmul_rn(p[i], p[i]));
    red[lane] = acc;
  }
  float h0 = __fadd_rn(__fadd_rn(__fadd_rn(red[0], red[1]), __fadd_rn(red[2], red[3])),
                       __fadd_rn(__fadd_rn(red[4], red[5]), __fadd_rn(red[6], red[7])));
  float h1 = __fadd_rn(__fadd_rn(__fadd_rn(red[8], red[9]), __fadd_rn(red[10], red[11])),
                       __fadd_rn(__fadd_rn(red[12], red[13]), __fadd_rn(red[14], red[15])));
  return __fadd_rn(h0, h1);
}
#pragma clang fp contract(fast)

// ---- kernel 1: prep — z,e -> i8 lane-ordered granules; zero cnt/loss/ctr ----
__global__ __launch_bounds__(256) void prep_kernel(const float* __restrict__ z,
                                                   const float* __restrict__ e,
                                                   char* __restrict__ zb8,
                                                   char* __restrict__ eb8,
                                                   int* __restrict__ g_cnt,
                                                   float* __restrict__ loss_ws,
                                                   int* __restrict__ ctr) {
  const int blk = blockIdx.x;
  if (blk < 512) {
    __shared__ float t[256][33];
    const int b = blk >> 5, h = blk & 31;
    const int w = threadIdx.x & 31, cc = threadIdx.x >> 5;
    const float* src = z + (size_t)b * 262144 + h * 32 + w;
#pragma unroll
    for (int c0 = 0; c0 < 256; c0 += 8) t[c0 + cc][w] = src[(size_t)(c0 + cc) * 1024];
    if (threadIdx.x < 32) g_cnt[blk * 32 + threadIdx.x] = 0;
    if (blk == 0 && threadIdx.x == 0) { *loss_ws = 0.f; *ctr = 0; }
    __syncthreads();
#pragma unroll
    for (int gi = 0; gi < 2; ++gi) {
      const int g = gi * 256 + threadIdx.x;
      const int kb = g >> 7, l4 = (g >> 5) & 3, w2 = g & 31;
      const int c0 = kb * 64 + l4 * 16;
      union { char c[16]; i32x4 v; } u;
#pragma unroll
      for (int j = 0; j < 16; ++j) u.c[j] = q8(t[c0 + j][w2], 16.0f);
      const int tile = blk * 2 + (w2 >> 4);
      *(i32x4*)(zb8 + (size_t)tile * 4096 + (size_t)(kb * 64 + l4 * 16 + (w2 & 15)) * 16) = u.v;
    }
  } else {
    const int G = (blk - 512) * 256 + threadIdx.x;
    const int tile = G >> 8, r = G & 255;
    const int kb = r >> 6, lane = r & 63;
    const int l4 = lane >> 4, l15 = lane & 15;
    const float* s = e + (size_t)(tile * 16 + l15) * 256 + kb * 64 + l4 * 16;
    union { char c[16]; i32x4 v; } u;
#pragma unroll
    for (int j = 0; j < 16; ++j) u.c[j] = q8(s[j], 1048576.0f);
    *(i32x4*)(eb8 + (size_t)G * 16) = u.v;
  }
}

// ---- kernel 2: streaming i8 MFMA scores ----
// 32 rows/block (a[2][4]=32 VGPR), grid 1024, launch_bounds(512,6) -> 85-reg
// budget, 3 blocks/CU = 6 waves/SIMD. VALU diet: sync every 4 chunks,
// ballot-gated push slots, unroll(1) on the chunk loop to cap live registers.
__global__ __launch_bounds__(512, 6) void scores_kernel(const char* __restrict__ zb8,
                                                        const char* __restrict__ eb8,
                                                        int* __restrict__ g_cnt,
                                                        char* __restrict__ cand) {
  __shared__ int s_rm[32];
  __shared__ u32 s_cnt[32][8];
  const int tid = threadIdx.x;
  const int wave = tid >> 6, lane = tid & 63;
  const int l15 = lane & 15, l4 = lane >> 4;
  const int row0 = (int)(blockIdx.x >> 1) * 32;
  const int half = (int)(blockIdx.x & 1);
  const int code0 = half * 4096;
  const int grp = half * 8 + wave;
  u16* cand16 = (u16*)cand;
  if (tid < 32) s_rm[tid] = INT_MIN;
  if (tid < 256) s_cnt[tid >> 3][tid & 7] = 0;

  i32x4 a[2][4];
#pragma unroll
  for (int rt = 0; rt < 2; ++rt) {
    const i32x4* ab = (const i32x4*)(zb8 + (size_t)((row0 >> 4) + rt) * 4096);
#pragma unroll
    for (int kb = 0; kb < 4; ++kb) a[rt][kb] = ab[kb * 64 + lane];
  }
  __syncthreads();   // s_rm/s_cnt init visible

  const i32x4* ebase = (const i32x4*)eb8 + (size_t)(code0 >> 4) * 256;
  int lmax[2][4];

#define COMPUTE(CH, ACC)                                                          \
  i32x4 ACC[2] = {{0,0,0,0},{0,0,0,0}};                                           \
  {                                                                               \
    const i32x4* bt = ebase + (size_t)((CH) * 8 + wave) * 256;                    \
    i32x4 bf0 = bt[lane], bf1 = bt[64 + lane], bf2 = bt[128 + lane], bf3 = bt[192 + lane]; \
    _Pragma("unroll")                                                             \
    for (int rt = 0; rt < 2; ++rt) {                                              \
      ACC[rt] = __builtin_amdgcn_mfma_i32_16x16x64_i8(a[rt][0], bf0, ACC[rt], 0, 0, 0); \
      ACC[rt] = __builtin_amdgcn_mfma_i32_16x16x64_i8(a[rt][1], bf1, ACC[rt], 0, 0, 0); \
      ACC[rt] = __builtin_amdgcn_mfma_i32_16x16x64_i8(a[rt][2], bf2, ACC[rt], 0, 0, 0); \
      ACC[rt] = __builtin_amdgcn_mfma_i32_16x16x64_i8(a[rt][3], bf3, ACC[rt], 0, 0, 0); \
    }                                                                             \
  }

// s_rm is monotone (atomicMax only, never reset) -> one relaxed barrier is safe;
// drain LDS only so in-flight global loads survive the barrier.
#define SYNC_THR()                                                               \
  {                                                                              \
    _Pragma("unroll")                                                            \
    for (int rt = 0; rt < 2; ++rt)                                               \
      _Pragma("unroll")                                                          \
      for (int r = 0; r < 4; ++r) {                                              \
        int m = rowmax16(lmax[rt][r]);                                           \
        if (l15 == 0) atomicMax(&s_rm[rt * 16 + l4 * 4 + r], m);                 \
      }                                                                          \
    asm volatile("s_waitcnt lgkmcnt(0)\n\ts_barrier" ::: "memory");              \
    _Pragma("unroll")                                                            \
    for (int rt = 0; rt < 2; ++rt)                                               \
      _Pragma("unroll")                                                          \
      for (int r = 0; r < 4; ++r)                                                \
        lmax[rt][r] = max(lmax[rt][r], s_rm[rt * 16 + l4 * 4 + r]);              \
  }

  // seed: chunks 0..3 (512 codes), maxes only — no pushes against a cold threshold
#pragma unroll 1
  for (int ch = 0; ch < 4; ++ch) {
    COMPUTE(ch, acc);
    if (ch == 0) {
#pragma unroll
      for (int rt = 0; rt < 2; ++rt)
#pragma unroll
        for (int r = 0; r < 4; ++r) lmax[rt][r] = acc[rt][r];
    } else {
#pragma unroll
      for (int rt = 0; rt < 2; ++rt)
#pragma unroll
        for (int r = 0; r < 4; ++r) lmax[rt][r] = max(lmax[rt][r], acc[rt][r]);
    }
  }
  SYNC_THR();

#pragma unroll 1
  for (int ch = 0; ch < 32; ++ch) {
    COMPUTE(ch, acc);
#pragma unroll
    for (int rt = 0; rt < 2; ++rt)
#pragma unroll
      for (int r = 0; r < 4; ++r) {
        const int v = acc[rt][r];
        const bool p = v > lmax[rt][r] - MARGIN_I;   // superset of final set
        if (__any(p)) {                              // scalar skip: pushes are rare
          if (p) {
            const int rl = rt * 16 + l4 * 4 + r;
            u32 q = atomicAdd(&s_cnt[rl][wave], 1u); // LDS atomic (fast path)
            if (q < GCAP) {
              cand16[(size_t)(row0 + rl) * 128 + grp * GCAP + q] =
                  (u16)(code0 + ch * 128 + wave * 16 + l15);
            } else {                                 // rare spill tier
              int o = atomicAdd(&g_cnt[row0 + rl], 1);
              if (o < OCAP)
                cand16[(size_t)(row0 + rl) * 128 + 96 + o] =
                    (u16)(code0 + ch * 128 + wave * 16 + l15);
            }
          }
        }
        lmax[rt][r] = max(lmax[rt][r], v);
      }
    if ((ch & 3) == 3 && ch != 31) SYNC_THR();
  }
#undef COMPUTE
#undef SYNC_THR

  // write out per-(row,group) counts — each wave owns its groups exclusively
  __syncthreads();
  if (tid < 256) {
    const int rl = tid >> 3, w = tid & 7;
    u32 c = s_cnt[rl][w];
    cand[(size_t)(row0 + rl) * 256 + 240 + half * 8 + w] = (u8)(c > 255u ? 255u : c);
  }
}

// ---- kernel 3: pair-compacted numpy-replica rescore + z_st gather + loss ----
__global__ __launch_bounds__(256) void rescore_fin_kernel(const float* __restrict__ z,
                                                          const float* __restrict__ emb,
                                                          const int* __restrict__ g_cnt,
                                                          const char* __restrict__ cand,
                                                          float* __restrict__ loss_ws,
                                                          int* __restrict__ ctr,
                                                          float* __restrict__ z_st,
                                                          float* __restrict__ out_loss,
                                                          float* __restrict__ out_idx) {
  __shared__ float zrows[32][257];
  __shared__ float red_s[4][16];
  __shared__ float A_s[32], D_s[32];
  __shared__ u64 best_s[32];
  __shared__ int widx_s[32], starts[33], ovf_list[32], rowtot[32];
  __shared__ int nP, nOvf;
  __shared__ u8 cnts8[32][17];
  __shared__ u16 grpoff[32][17];
  __shared__ u8 prow[32 * 120];
  __shared__ u16 pidx[32 * 120];
  const int bh = blockIdx.x;
  const int b = bh >> 5, h = bh & 31;
  const int n0 = bh * 32;
  const int wave = threadIdx.x >> 6, lane = threadIdx.x & 63;
  const u16* cand16 = (const u16*)cand;
  {
    const float* src = z + (size_t)b * 262144 + h * 32;
    const int w = threadIdx.x & 31, c8 = threadIdx.x >> 5;
#pragma unroll
    for (int c0 = 0; c0 < 256; c0 += 8) {
      int c = c0 + c8;
      zrows[w][c] = src[(size_t)c * 1024 + w];
    }
  }
  if (threadIdx.x < 32) best_s[threadIdx.x] = ~0ull;
  __syncthreads();

  for (int j = 0; j < 8; ++j) {
    const int r = wave * 8 + j;
    float A = np_rowA(zrows[r], lane, red_s[wave]);
    if (lane == 0) A_s[r] = A;
  }
  if (threadIdx.x < 32) {
    const int r = threadIdx.x;
    const u32* cw = (const u32*)(cand + (size_t)(n0 + r) * 256 + 240);
    u32 wv[4] = {cw[0], cw[1], cw[2], cw[3]};
    int tot = 0;
#pragma unroll
    for (int k = 0; k < 16; ++k) {
      int c = (int)((wv[k >> 2] >> ((k & 3) * 8)) & 0xff);
      int cc = c > GCAP ? GCAP : c;
      cnts8[r][k] = (u8)cc;
      grpoff[r][k] = (u16)tot;
      tot += cc;
    }
    const int ov = g_cnt[n0 + r];
    const int oc = ov > OCAP ? OCAP : ov;
    cnts8[r][16] = (u8)oc;
    grpoff[r][16] = (u16)tot;
    tot += oc;
    rowtot[r] = (ov > OCAP) ? 0 : tot;   // 0 -> block-wide full-scan fallback
  }
  __syncthreads();
  if (threadIdx.x == 0) {
    int acc = 0, no = 0;
    for (int r = 0; r < 32; ++r) {
      starts[r] = acc;
      acc += rowtot[r];
      if (rowtot[r] == 0) ovf_list[no++] = r;
    }
    starts[32] = acc; nP = acc; nOvf = no;
  }
  __syncthreads();
  for (int u = threadIdx.x; u < 512; u += 256) {
    const int r = u >> 4, g = u & 15;
    if (rowtot[r]) {
      const int c = cnts8[r][g];
      const int base = starts[r] + grpoff[r][g];
      const int sb = g * GCAP;
      for (int j = 0; j < c; ++j) {
        prow[base + j] = (u8)r;
        pidx[base + j] = cand16[(size_t)(n0 + r) * 128 + sb + j];
      }
    }
  }
  if (threadIdx.x < 32) {
    const int r = threadIdx.x;
    if (rowtot[r]) {
      const int c = cnts8[r][16];
      const int base = starts[r] + grpoff[r][16];
      for (int j = 0; j < c; ++j) {
        prow[base + j] = (u8)r;
        pidx[base + j] = cand16[(size_t)(n0 + r) * 128 + 96 + j];
      }
    }
  }
  __syncthreads();

  const int P = nP;
  for (int p = threadIdx.x; p < P; p += 256) {
    const int r = prow[p], idx = (int)pidx[p];
    float D = np_dist(zrows[r], emb + (size_t)idx * 256, A_s[r]);
    u64 key = ((u64)__float_as_uint(D) << 16) | (u32)idx;
    atomicMin(&best_s[r], key);
  }
  __syncthreads();

  // overflow fallback (spill>OCAP, ~never): block-wide scan
  for (int i = 0; i < nOvf; ++i) {
    const int r = ovf_list[i];
    for (int idx = threadIdx.x; idx < NCODE; idx += 256) {
      float D = np_dist(zrows[r], emb + (size_t)idx * 256, A_s[r]);
      u64 k = ((u64)__float_as_uint(D) << 16) | (u32)idx;
      atomicMin(&best_s[r], k);
    }
  }
  if (nOvf) __syncthreads();

  if (threadIdx.x < 32) {
    const int r = threadIdx.x;
    const u64 k = best_s[r];
    const int bidx = (int)(k & 0xFFFF);
    widx_s[r] = bidx;
    out_idx[n0 + r] = (float)bidx;
    D_s[r] = __uint_as_float((u32)(k >> 16));
  }
  __syncthreads();
  if (threadIdx.x == 0) {
    float s = 0.f;
    for (int r = 0; r < 32; ++r) s += D_s[r];
    atomicAdd(loss_ws, s);
    __threadfence();
    int t = atomicAdd(ctr, 1);
    if (t == 511)
      *out_loss = atomicAdd(loss_ws, 0.0f) * (1.25f / 4194304.0f);
  }

  for (int wi = 0; wi < 32; ++wi)
    zrows[wi][threadIdx.x] = emb[(size_t)widx_s[wi] * 256 + threadIdx.x];
  __syncthreads();
  const int w = threadIdx.x & 31, c0 = threadIdx.x >> 5;
  float* dst = z_st + (size_t)b * 262144 + h * 32 + w;
#pragma unroll
  for (int cj = 0; cj < 32; ++cj) {
    int c = c0 + cj * 8;
    dst[(size_t)c * 1024] = zrows[w][c];
  }
}

extern "C" void kernel_launch(void* const* d_in, const int* in_sizes, int n_in,
                              void* d_out, int out_size, void* d_ws, size_t ws_size,
                              hipStream_t stream) {
  const float* z = (const float*)d_in[0];     // fp32 [16,256,32,32]
  const float* emb = (const float*)d_in[1];   // fp32 [8192,256]
  char* ws = (char*)d_ws;
  char* zb8 = ws + OFF_ZB8;
  char* eb8 = ws + OFF_EB8;
  int* g_cnt = (int*)(ws + OFF_CNT);
  char* cand = ws + OFF_CAND;
  float* loss_ws = (float*)(ws + OFF_LOSS);
  int* ctr = (int*)(ws + OFF_CTR);
  float* out = (float*)d_out;
  float* out_loss = out + ZN;       // output 1
  float* out_idx = out + ZN + 1;    // output 2

  prep_kernel<<<1024, 256, 0, stream>>>(z, emb, zb8, eb8, g_cnt, loss_ws, ctr);
  scores_kernel<<<1024, 512, 0, stream>>>(zb8, eb8, g_cnt, cand);
  rescore_fin_kernel<<<512, 256, 0, stream>>>(z, emb, g_cnt, cand, loss_ws, ctr,
                                              out, out_loss, out_idx);
}

// Round 6
// 215.326 us; speedup vs baseline: 2.7205x; 1.0912x over previous
//
#include <hip/hip_runtime.h>

typedef __attribute__((ext_vector_type(4))) int i32x4;
typedef unsigned short u16;
typedef unsigned char u8;
typedef unsigned int u32;
typedef unsigned long long u64;

static constexpr int NROW = 16384;   // b*h*w
static constexpr int NCODE = 8192;
static constexpr int ZN = 4194304;   // b*c*h*w
static constexpr int MARGIN_I = 4200;   // 2.5e-4 * 2^24

// Candidate row layout (256 B per row):
//   u16 slots[96]   : 16 groups (code-half*8 + wave) x 6 slots   (bytes 0..191)
//   u16 ovf[24]     : per-row spill list                          (bytes 192..239)
//   u8  counts[16]  : per-group push counts (saturated)           (bytes 240..255)
// Spill count lives in g_cnt[row]. Full-scan fallback iff g_cnt[row] > OCAP.
static constexpr int GCAP = 6;
static constexpr int OCAP = 24;

// workspace layout (bytes) — 10.6 MB
static constexpr size_t OFF_ZB8  = 0;          // i8 granules z  4 MB
static constexpr size_t OFF_EB8  = 4194304;    // i8 granules e  2 MB
static constexpr size_t OFF_CNT  = 6291456;    // int [NROW] spill counters
static constexpr size_t OFF_CAND = 6356992;    // 256 B per row  4 MB
static constexpr size_t OFF_LOSS = 10551296;   // float
static constexpr size_t OFF_CTR  = 10551300;   // int

__device__ __forceinline__ char q8(float v, float s) {
  int x = __float2int_rn(v * s);
  x = x < -128 ? -128 : (x > 127 ? 127 : x);
  return (char)x;
}

// max over each 16-lane row via DPP row_ror (VALU pipe, no LDS traffic)
__device__ __forceinline__ int rowmax16(int m) {
  m = max(m, __builtin_amdgcn_update_dpp(m, m, 0x121, 0xf, 0xf, false)); // ror:1
  m = max(m, __builtin_amdgcn_update_dpp(m, m, 0x122, 0xf, 0xf, false)); // ror:2
  m = max(m, __builtin_amdgcn_update_dpp(m, m, 0x124, 0xf, 0xf, false)); // ror:4
  m = max(m, __builtin_amdgcn_update_dpp(m, m, 0x128, 0xf, 0xf, false)); // ror:8
  return m;
}

// ---- numpy fp32 replica (verified rounds 4-9; no FMA contraction) ----
// zr must be 16B-aligned; scalars re-sourced from float4 components in the
// EXACT same operation order as the scalar version (bit-identical).
#pragma clang fp contract(off)
__device__ float np_dist(const float* zr, const float* __restrict__ er, float A) {
  const float4* e4 = (const float4*)er;
  const float4* z4 = (const float4*)zr;
  float s0 = 0.f, s1 = 0.f, s2 = 0.f, s3 = 0.f;
#pragma unroll 4
  for (int i16 = 0; i16 < 16; ++i16) {
    float4 ea = e4[i16 * 4 + 0], eb = e4[i16 * 4 + 1];
    float4 ec = e4[i16 * 4 + 2], ed = e4[i16 * 4 + 3];
    float4 za = z4[i16 * 4 + 0], zb = z4[i16 * 4 + 1];
    float4 zc = z4[i16 * 4 + 2], zd = z4[i16 * 4 + 3];
    s0 = __fadd_rn(__fmul_rn(za.x, ea.x),
         __fadd_rn(__fmul_rn(zb.x, eb.x),
         __fadd_rn(__fmul_rn(zc.x, ec.x),
         __fadd_rn(__fmul_rn(zd.x, ed.x), s0))));
    s1 = __fadd_rn(__fmul_rn(za.y, ea.y),
         __fadd_rn(__fmul_rn(zb.y, eb.y),
         __fadd_rn(__fmul_rn(zc.y, ec.y),
         __fadd_rn(__fmul_rn(zd.y, ed.y), s1))));
    s2 = __fadd_rn(__fmul_rn(za.z, ea.z),
         __fadd_rn(__fmul_rn(zb.z, eb.z),
         __fadd_rn(__fmul_rn(zc.z, ec.z),
         __fadd_rn(__fmul_rn(zd.z, ed.z), s2))));
    s3 = __fadd_rn(__fmul_rn(za.w, ea.w),
         __fadd_rn(__fmul_rn(zb.w, eb.w),
         __fadd_rn(__fmul_rn(zc.w, ec.w),
         __fadd_rn(__fmul_rn(zd.w, ed.w), s3))));
  }
  float C = __fadd_rn(__fadd_rn(s0, s1), __fadd_rn(s2, s3));
  return __fadd_rn(A, -(2.0f * C));
}

// A = np pairwise-sum replica of ||z||^2 (verified rounds 4-9).
__device__ float np_rowA(const float* zrow, int lane, volatile float* red) {
  if (lane < 16) {
    const int half = lane >> 3, jj = lane & 7;
    const float* p = zrow + half * 128 + jj;
    float acc = __fmul_rn(p[0], p[0]);
    for (int i = 8; i < 128; i += 8) acc = __fadd_rn(acc, __fmul_rn(p[i], p[i]));
    red[lane] = acc;
  }
  float h0 = __fadd_rn(__fadd_rn(__fadd_rn(red[0], red[1]), __fadd_rn(red[2], red[3])),
                       __fadd_rn(__fadd_rn(red[4], red[5]), __fadd_rn(red[6], red[7])));
  float h1 = __fadd_rn(__fadd_rn(__fadd_rn(red[8], red[9]), __fadd_rn(red[10], red[11])),
                       __fadd_rn(__fadd_rn(red[12], red[13]), __fadd_rn(red[14], red[15])));
  return __fadd_rn(h0, h1);
}
#pragma clang fp contract(fast)

// ---- kernel 1: prep — z,e -> i8 lane-ordered granules; zero cnt/loss/ctr ----
__global__ __launch_bounds__(256) void prep_kernel(const float* __restrict__ z,
                                                   const float* __restrict__ e,
                                                   char* __restrict__ zb8,
                                                   char* __restrict__ eb8,
                                                   int* __restrict__ g_cnt,
                                                   float* __restrict__ loss_ws,
                                                   int* __restrict__ ctr) {
  const int blk = blockIdx.x;
  if (blk < 512) {
    __shared__ float t[256][33];
    const int b = blk >> 5, h = blk & 31;
    const int w = threadIdx.x & 31, cc = threadIdx.x >> 5;
    const float* src = z + (size_t)b * 262144 + h * 32 + w;
#pragma unroll
    for (int c0 = 0; c0 < 256; c0 += 8) t[c0 + cc][w] = src[(size_t)(c0 + cc) * 1024];
    if (threadIdx.x < 32) g_cnt[blk * 32 + threadIdx.x] = 0;
    if (blk == 0 && threadIdx.x == 0) { *loss_ws = 0.f; *ctr = 0; }
    __syncthreads();
#pragma unroll
    for (int gi = 0; gi < 2; ++gi) {
      const int g = gi * 256 + threadIdx.x;
      const int kb = g >> 7, l4 = (g >> 5) & 3, w2 = g & 31;
      const int c0 = kb * 64 + l4 * 16;
      union { char c[16]; i32x4 v; } u;
#pragma unroll
      for (int j = 0; j < 16; ++j) u.c[j] = q8(t[c0 + j][w2], 16.0f);
      const int tile = blk * 2 + (w2 >> 4);
      *(i32x4*)(zb8 + (size_t)tile * 4096 + (size_t)(kb * 64 + l4 * 16 + (w2 & 15)) * 16) = u.v;
    }
  } else {
    const int G = (blk - 512) * 256 + threadIdx.x;
    const int tile = G >> 8, r = G & 255;
    const int kb = r >> 6, lane = r & 63;
    const int l4 = lane >> 4, l15 = lane & 15;
    const float* s = e + (size_t)(tile * 16 + l15) * 256 + kb * 64 + l4 * 16;
    union { char c[16]; i32x4 v; } u;
#pragma unroll
    for (int j = 0; j < 16; ++j) u.c[j] = q8(s[j], 1048576.0f);
    *(i32x4*)(eb8 + (size_t)G * 16) = u.v;
  }
}

// ---- kernel 2: streaming i8 MFMA scores ----
// launch_bounds(512,3): empirically arg2 acts as blocks/CU -> ~85-reg budget.
// Live set ~80 (a[2][4]=32 + bf 16 + acc 8 + lmax 8 + addr) fits -> no spill,
// 3 blocks/CU = 24 waves/CU. (512,6) last round gave a 40-reg budget and 53 MB
// of scratch spill traffic.
__global__ __launch_bounds__(512, 3) void scores_kernel(const char* __restrict__ zb8,
                                                        const char* __restrict__ eb8,
                                                        int* __restrict__ g_cnt,
                                                        char* __restrict__ cand) {
  __shared__ int s_rm[32];
  __shared__ u32 s_cnt[32][8];
  const int tid = threadIdx.x;
  const int wave = tid >> 6, lane = tid & 63;
  const int l15 = lane & 15, l4 = lane >> 4;
  const int row0 = (int)(blockIdx.x >> 1) * 32;
  const int half = (int)(blockIdx.x & 1);
  const int code0 = half * 4096;
  const int grp = half * 8 + wave;
  u16* cand16 = (u16*)cand;
  if (tid < 32) s_rm[tid] = INT_MIN;
  if (tid < 256) s_cnt[tid >> 3][tid & 7] = 0;

  i32x4 a[2][4];
#pragma unroll
  for (int rt = 0; rt < 2; ++rt) {
    const i32x4* ab = (const i32x4*)(zb8 + (size_t)((row0 >> 4) + rt) * 4096);
#pragma unroll
    for (int kb = 0; kb < 4; ++kb) a[rt][kb] = ab[kb * 64 + lane];
  }
  __syncthreads();   // s_rm/s_cnt init visible

  const i32x4* ebase = (const i32x4*)eb8 + (size_t)(code0 >> 4) * 256;
  int lmax[2][4];

#define COMPUTE(CH, ACC)                                                          \
  i32x4 ACC[2] = {{0,0,0,0},{0,0,0,0}};                                           \
  {                                                                               \
    const i32x4* bt = ebase + (size_t)((CH) * 8 + wave) * 256;                    \
    i32x4 bf0 = bt[lane], bf1 = bt[64 + lane], bf2 = bt[128 + lane], bf3 = bt[192 + lane]; \
    _Pragma("unroll")                                                             \
    for (int rt = 0; rt < 2; ++rt) {                                              \
      ACC[rt] = __builtin_amdgcn_mfma_i32_16x16x64_i8(a[rt][0], bf0, ACC[rt], 0, 0, 0); \
      ACC[rt] = __builtin_amdgcn_mfma_i32_16x16x64_i8(a[rt][1], bf1, ACC[rt], 0, 0, 0); \
      ACC[rt] = __builtin_amdgcn_mfma_i32_16x16x64_i8(a[rt][2], bf2, ACC[rt], 0, 0, 0); \
      ACC[rt] = __builtin_amdgcn_mfma_i32_16x16x64_i8(a[rt][3], bf3, ACC[rt], 0, 0, 0); \
    }                                                                             \
  }

// s_rm is monotone (atomicMax only, never reset) -> one relaxed barrier is safe;
// drain LDS only so in-flight global loads survive the barrier.
#define SYNC_THR()                                                               \
  {                                                                              \
    _Pragma("unroll")                                                            \
    for (int rt = 0; rt < 2; ++rt)                                               \
      _Pragma("unroll")                                                          \
      for (int r = 0; r < 4; ++r) {                                              \
        int m = rowmax16(lmax[rt][r]);                                           \
        if (l15 == 0) atomicMax(&s_rm[rt * 16 + l4 * 4 + r], m);                 \
      }                                                                          \
    asm volatile("s_waitcnt lgkmcnt(0)\n\ts_barrier" ::: "memory");              \
    _Pragma("unroll")                                                            \
    for (int rt = 0; rt < 2; ++rt)                                               \
      _Pragma("unroll")                                                          \
      for (int r = 0; r < 4; ++r)                                                \
        lmax[rt][r] = max(lmax[rt][r], s_rm[rt * 16 + l4 * 4 + r]);              \
  }

  // seed: chunks 0..3 (512 codes), maxes only — no pushes against a cold threshold
#pragma unroll 1
  for (int ch = 0; ch < 4; ++ch) {
    COMPUTE(ch, acc);
    if (ch == 0) {
#pragma unroll
      for (int rt = 0; rt < 2; ++rt)
#pragma unroll
        for (int r = 0; r < 4; ++r) lmax[rt][r] = acc[rt][r];
    } else {
#pragma unroll
      for (int rt = 0; rt < 2; ++rt)
#pragma unroll
        for (int r = 0; r < 4; ++r) lmax[rt][r] = max(lmax[rt][r], acc[rt][r]);
    }
  }
  SYNC_THR();

#pragma unroll 1
  for (int ch = 0; ch < 32; ++ch) {
    COMPUTE(ch, acc);
#pragma unroll
    for (int rt = 0; rt < 2; ++rt)
#pragma unroll
      for (int r = 0; r < 4; ++r) {
        const int v = acc[rt][r];
        const bool p = v > lmax[rt][r] - MARGIN_I;   // superset of final set
        if (__any(p)) {                              // scalar skip: pushes are rare
          if (p) {
            const int rl = rt * 16 + l4 * 4 + r;
            u32 q = atomicAdd(&s_cnt[rl][wave], 1u); // LDS atomic (fast path)
            if (q < GCAP) {
              cand16[(size_t)(row0 + rl) * 128 + grp * GCAP + q] =
                  (u16)(code0 + ch * 128 + wave * 16 + l15);
            } else {                                 // rare spill tier
              int o = atomicAdd(&g_cnt[row0 + rl], 1);
              if (o < OCAP)
                cand16[(size_t)(row0 + rl) * 128 + 96 + o] =
                    (u16)(code0 + ch * 128 + wave * 16 + l15);
            }
          }
        }
        lmax[rt][r] = max(lmax[rt][r], v);
      }
    if ((ch & 3) == 3 && ch != 31) SYNC_THR();
  }
#undef COMPUTE
#undef SYNC_THR

  // write out per-(row,group) counts — each wave owns its groups exclusively
  __syncthreads();
  if (tid < 256) {
    const int rl = tid >> 3, w = tid & 7;
    u32 c = s_cnt[rl][w];
    cand[(size_t)(row0 + rl) * 256 + 240 + half * 8 + w] = (u8)(c > 255u ? 255u : c);
  }
}

// ---- kernel 3: pair-compacted numpy-replica rescore + z_st gather + loss ----
// 512 threads (2x latency hiding) + float4 LDS reads in np_dist (4x fewer
// LDS instructions — round-5 analysis: rescore was LDS-issue-bound on 256
// scalar ds_reads per np_dist). zrows stride 257->260 for 16B alignment.
__global__ __launch_bounds__(512) void rescore_fin_kernel(const float* __restrict__ z,
                                                          const float* __restrict__ emb,
                                                          const int* __restrict__ g_cnt,
                                                          const char* __restrict__ cand,
                                                          float* __restrict__ loss_ws,
                                                          int* __restrict__ ctr,
                                                          float* __restrict__ z_st,
                                                          float* __restrict__ out_loss,
                                                          float* __restrict__ out_idx) {
  __shared__ float zrows[32][260];
  __shared__ float red_s[8][16];
  __shared__ float A_s[32], D_s[32];
  __shared__ u64 best_s[32];
  __shared__ int widx_s[32], starts[33], ovf_list[32], rowtot[32];
  __shared__ int nP, nOvf;
  __shared__ u8 cnts8[32][17];
  __shared__ u16 grpoff[32][17];
  __shared__ u8 prow[32 * 120];
  __shared__ u16 pidx[32 * 120];
  const int bh = blockIdx.x;
  const int b = bh >> 5, h = bh & 31;
  const int n0 = bh * 32;
  const int tid = threadIdx.x;
  const int wave = tid >> 6, lane = tid & 63;
  const u16* cand16 = (const u16*)cand;
  {
    const float* src = z + (size_t)b * 262144 + h * 32;
    const int w = tid & 31, c16 = tid >> 5;   // c16: 0..15
#pragma unroll
    for (int c0 = 0; c0 < 256; c0 += 16) {
      int c = c0 + c16;
      zrows[w][c] = src[(size_t)c * 1024 + w];
    }
  }
  if (tid < 32) best_s[tid] = ~0ull;
  __syncthreads();

  for (int j = 0; j < 4; ++j) {
    const int r = wave * 4 + j;
    float A = np_rowA(zrows[r], lane, red_s[wave]);
    if (lane == 0) A_s[r] = A;
  }
  if (tid < 32) {
    const int r = tid;
    const u32* cw = (const u32*)(cand + (size_t)(n0 + r) * 256 + 240);
    u32 wv[4] = {cw[0], cw[1], cw[2], cw[3]};
    int tot = 0;
#pragma unroll
    for (int k = 0; k < 16; ++k) {
      int c = (int)((wv[k >> 2] >> ((k & 3) * 8)) & 0xff);
      int cc = c > GCAP ? GCAP : c;
      cnts8[r][k] = (u8)cc;
      grpoff[r][k] = (u16)tot;
      tot += cc;
    }
    const int ov = g_cnt[n0 + r];
    const int oc = ov > OCAP ? OCAP : ov;
    cnts8[r][16] = (u8)oc;
    grpoff[r][16] = (u16)tot;
    tot += oc;
    rowtot[r] = (ov > OCAP) ? 0 : tot;   // 0 -> block-wide full-scan fallback
  }
  __syncthreads();
  if (tid == 0) {
    int acc = 0, no = 0;
    for (int r = 0; r < 32; ++r) {
      starts[r] = acc;
      acc += rowtot[r];
      if (rowtot[r] == 0) ovf_list[no++] = r;
    }
    starts[32] = acc; nP = acc; nOvf = no;
  }
  __syncthreads();
  {
    const int r = tid >> 4, g = tid & 15;   // 512 threads cover [32][16]
    if (rowtot[r]) {
      const int c = cnts8[r][g];
      const int base = starts[r] + grpoff[r][g];
      const int sb = g * GCAP;
      for (int j = 0; j < c; ++j) {
        prow[base + j] = (u8)r;
        pidx[base + j] = cand16[(size_t)(n0 + r) * 128 + sb + j];
      }
    }
  }
  if (tid < 32) {
    const int r = tid;
    if (rowtot[r]) {
      const int c = cnts8[r][16];
      const int base = starts[r] + grpoff[r][16];
      for (int j = 0; j < c; ++j) {
        prow[base + j] = (u8)r;
        pidx[base + j] = cand16[(size_t)(n0 + r) * 128 + 96 + j];
      }
    }
  }
  __syncthreads();

  const int P = nP;
  for (int p = tid; p < P; p += 512) {
    const int r = prow[p], idx = (int)pidx[p];
    float D = np_dist(zrows[r], emb + (size_t)idx * 256, A_s[r]);
    u64 key = ((u64)__float_as_uint(D) << 16) | (u32)idx;
    atomicMin(&best_s[r], key);
  }
  __syncthreads();

  // overflow fallback (spill>OCAP, ~never): block-wide scan
  for (int i = 0; i < nOvf; ++i) {
    const int r = ovf_list[i];
    for (int idx = tid; idx < NCODE; idx += 512) {
      float D = np_dist(zrows[r], emb + (size_t)idx * 256, A_s[r]);
      u64 k = ((u64)__float_as_uint(D) << 16) | (u32)idx;
      atomicMin(&best_s[r], k);
    }
  }
  if (nOvf) __syncthreads();

  if (tid < 32) {
    const int r = tid;
    const u64 k = best_s[r];
    const int bidx = (int)(k & 0xFFFF);
    widx_s[r] = bidx;
    out_idx[n0 + r] = (float)bidx;
    D_s[r] = __uint_as_float((u32)(k >> 16));
  }
  __syncthreads();
  if (tid == 0) {
    float s = 0.f;
    for (int r = 0; r < 32; ++r) s += D_s[r];
    atomicAdd(loss_ws, s);
    __threadfence();
    int t = atomicAdd(ctr, 1);
    if (t == 511)
      *out_loss = atomicAdd(loss_ws, 0.0f) * (1.25f / 4194304.0f);
  }

  {
    const int col = tid & 255, hi = tid >> 8;
#pragma unroll
    for (int wi0 = 0; wi0 < 16; ++wi0) {
      const int wi = wi0 * 2 + hi;
      zrows[wi][col] = emb[(size_t)widx_s[wi] * 256 + col];
    }
  }
  __syncthreads();
  {
    const int w = tid & 31, c0 = (tid >> 5) & 7, hi = tid >> 8;
    float* dst = z_st + (size_t)b * 262144 + h * 32 + w;
#pragma unroll
    for (int cj = 0; cj < 16; ++cj) {
      int c = c0 + (cj * 2 + hi) * 8;
      dst[(size_t)c * 1024] = zrows[w][c];
    }
  }
}

extern "C" void kernel_launch(void* const* d_in, const int* in_sizes, int n_in,
                              void* d_out, int out_size, void* d_ws, size_t ws_size,
                              hipStream_t stream) {
  const float* z = (const float*)d_in[0];     // fp32 [16,256,32,32]
  const float* emb = (const float*)d_in[1];   // fp32 [8192,256]
  char* ws = (char*)d_ws;
  char* zb8 = ws + OFF_ZB8;
  char* eb8 = ws + OFF_EB8;
  int* g_cnt = (int*)(ws + OFF_CNT);
  char* cand = ws + OFF_CAND;
  float* loss_ws = (float*)(ws + OFF_LOSS);
  int* ctr = (int*)(ws + OFF_CTR);
  float* out = (float*)d_out;
  float* out_loss = out + ZN;       // output 1
  float* out_idx = out + ZN + 1;    // output 2

  prep_kernel<<<1024, 256, 0, stream>>>(z, emb, zb8, eb8, g_cnt, loss_ws, ctr);
  scores_kernel<<<1024, 512, 0, stream>>>(zb8, eb8, g_cnt, cand);
  rescore_fin_kernel<<<512, 512, 0, stream>>>(z, emb, g_cnt, cand, loss_ws, ctr,
                                              out, out_loss, out_idx);
}